// Round 6
// baseline (370.371 us; speedup 1.0000x reference)
//
#include <hip/hip_runtime.h>
#include <hip/hip_bf16.h>
#include <math.h>

// BiMambaEncoderLayer: B=2, L=2048, D_MODEL=512, ED=1024, N=16, DCONV=4,
// DT_RANK=32, D_FF=1024. f32 in/out.
// Round-21: scan8 -> scan9. Diagnosis from two failed FLOP-reduction
// attempts: the scan is serial-latency-bound (6-level dependent shfl KS
// chain + barrier, x16 states ~ 3800 cyc/block), not VALU-bound. scan9 =
// scan6's exact math with the n-loop unrolled x2: two independent states'
// walks + KS chains interleaved in straight-line code (each hides the
// other's DS latency), barriers halved 16->8. All sWp/sWs slots distinct
// across the loop -> no reuse race. bgemm3 BK=64 kept (measured win).
// 11 dispatches, 48.4 MiB workspace.

#define BD 2
#define LD 2048
#define DMODEL 512
#define EDIM 1024
#define NST 16
#define DTR 32
#define DFF 1024
#define MROWS (BD*LD)   // 4096

typedef __hip_bfloat16 bf16;
typedef __bf16 bf16x8 __attribute__((ext_vector_type(8)));
typedef __bf16 bf16x4 __attribute__((ext_vector_type(4)));
typedef float  f32x4  __attribute__((ext_vector_type(4)));

__device__ __forceinline__ float sig_(float x) { return 1.f / (1.f + __expf(-x)); }

// async 16B global->LDS (wave-uniform LDS base, per-lane global addr)
__device__ __forceinline__ void glds16(const void* g, void* l)
{
    __builtin_amdgcn_global_load_lds(
        (const __attribute__((address_space(1))) void*)g,
        (__attribute__((address_space(3))) void*)l, 16, 0, 0);
}

// ---------------- prep: all weight transposes + x->bf16, one dispatch --------
// [0,2048) xconv | [2048,4096) inwT | [4096,5120) outwT | [5120,5632) fw1T |
// [5632,6144) fw2T | [6144,6272) xpT | [6272,6336) dtwT
__global__ __launch_bounds__(256)
void prep_k(const float* __restrict__ x, bf16* __restrict__ xbf,
            const float* __restrict__ inw_f, const float* __restrict__ inw_b,
            bf16* __restrict__ inwT,
            const float* __restrict__ outw_f, const float* __restrict__ outw_b,
            bf16* __restrict__ outwT,
            const float* __restrict__ fw1, bf16* __restrict__ fw1T,
            const float* __restrict__ fw2, bf16* __restrict__ fw2T,
            const float* __restrict__ xp_f, const float* __restrict__ xp_b,
            bf16* __restrict__ xpT,
            const float* __restrict__ dtw_f, const float* __restrict__ dtw_b,
            bf16* __restrict__ dtwT)
{
    const int bid = blockIdx.x, tid = threadIdx.x;
    if (bid < 2048) {
        size_t i = (size_t)bid * 1024 + tid * 4;
        float4 v = *(const float4*)(x + i);
        bf16* o = xbf + i;
        o[0] = __float2bfloat16(v.x); o[1] = __float2bfloat16(v.y);
        o[2] = __float2bfloat16(v.z); o[3] = __float2bfloat16(v.w);
        return;
    }
    const float* W; bf16* WT; int R, C, cx, ry;
    if (bid < 4096) {
        int d = (bid - 2048) >> 10, t = (bid - 2048) & 1023;
        W = d ? inw_b : inw_f; WT = inwT + (size_t)d * 2048 * 512;
        R = 512; C = 2048; cx = t & 63; ry = t >> 6;
    } else if (bid < 5120) {
        int d = (bid - 4096) >> 9, t = (bid - 4096) & 511;
        W = d ? outw_b : outw_f; WT = outwT + (size_t)d * 512 * 1024;
        R = 1024; C = 512; cx = t & 15; ry = t >> 4;
    } else if (bid < 5632) {
        int t = bid - 5120; W = fw1; WT = fw1T; R = 512; C = 1024;
        cx = t & 31; ry = t >> 5;
    } else if (bid < 6144) {
        int t = bid - 5632; W = fw2; WT = fw2T; R = 1024; C = 512;
        cx = t & 15; ry = t >> 4;
    } else if (bid < 6272) {
        int d = (bid - 6144) >> 6, t = (bid - 6144) & 63;
        W = d ? xp_b : xp_f; WT = xpT + (size_t)d * 64 * 1024;
        R = 1024; C = 64; cx = t & 1; ry = t >> 1;
    } else {
        int d = (bid - 6272) >> 5, t = (bid - 6272) & 31;
        W = d ? dtw_b : dtw_f; WT = dtwT + (size_t)d * 1024 * DTR;
        R = 32; C = 1024; cx = t; ry = 0;
    }
    __shared__ float tt[32][33];
    const int c0 = cx * 32, r0 = ry * 32;
    const int col = tid & 31, rr = tid >> 5;
#pragma unroll
    for (int p = 0; p < 4; ++p)
        tt[p * 8 + rr][col] = W[(size_t)(r0 + p * 8 + rr) * C + c0 + col];
    __syncthreads();
#pragma unroll
    for (int p = 0; p < 4; ++p)
        WT[(size_t)(c0 + p * 8 + rr) * R + r0 + col] =
            __float2bfloat16(tt[col][p * 8 + rr]);
}

// ---------------- bgemm3: 128xBN MFMA GEMM, BK=64, global_load_lds ----------
template<int BN, int MODE, bool FLIPD1, bool CATK>
__global__ __launch_bounds__(256)
void bgemm3_k(const bf16* __restrict__ A, size_t Astr, int lda,
              const bf16* __restrict__ BT, size_t Bstr, int ldb,
              const float* __restrict__ bias,
              bf16* __restrict__ Cb, size_t Cstr, int ldc,
              const bf16* __restrict__ mp, size_t mpStr,
              float* __restrict__ outp, int K)
{
    constexpr int BM = 128, BK = 64;
    constexpr int FRm = 4, FRn = BN / 32;
    constexpr int KH = DFF;   // concat-K half length (1024)
    __shared__ __align__(16) bf16 As[BM][BK];
    __shared__ __align__(16) bf16 Bs[BN][BK];
    const int tid = threadIdx.x;
    const int dir = blockIdx.z;
    const bool flip = FLIPD1 && (dir == 1);
    const bf16* Ad = A + (CATK ? (size_t)0 : (size_t)dir * Astr);
    const bf16* Bd = BT + (size_t)dir * Bstr;
    const int bm = blockIdx.y * BM, bn = blockIdx.x * BN;
    const int wave = tid >> 6, lane = tid & 63;
    const int wm = (wave >> 1) * 64, wn = (wave & 1) * (BN / 2);
    const int lm = lane & 15, lq = lane >> 4;
    const int lrow = lane >> 3, lcol = (lane & 7) * 8;   // 8 rows x 128B / wave
    f32x4 acc[FRm][FRn] = {};

    for (int k0 = 0; k0 < K; k0 += BK) {
        const bf16* Ab = Ad;
        int ka = k0;
        if (CATK && k0 >= KH) { Ab = A + Astr; ka = k0 - KH; }
        const int kb = CATK ? (k0 & (KH - 1)) : k0;
        // stage A tile (128x64 bf16 = 16KB): 4 rounds x 4 waves x 8 rows
#pragma unroll
        for (int c = 0; c < 4; ++c) {
            int row = c * 32 + wave * 8 + lrow;
            int gm = bm + row;
            if (flip) gm = (gm & ~(LD - 1)) + (LD - 1 - (gm & (LD - 1)));
            glds16(Ab + (size_t)gm * lda + ka + lcol,
                   &As[c * 32 + wave * 8][0]);
        }
        // stage B tile (BNx64): BN/32 rounds
#pragma unroll
        for (int c = 0; c < BN / 32; ++c) {
            int row = c * 32 + wave * 8 + lrow;
            glds16(Bd + (size_t)(bn + row) * ldb + kb + lcol,
                   &Bs[c * 32 + wave * 8][0]);
        }
        __syncthreads();   // drains vmcnt -> staging complete

#pragma unroll
        for (int kh = 0; kh < 2; ++kh) {
            bf16x8 af[FRm], bfr[FRn];
#pragma unroll
            for (int i = 0; i < FRm; ++i)
                af[i] = *(const bf16x8*)&As[wm + 16 * i + lm][kh * 32 + lq * 8];
#pragma unroll
            for (int j = 0; j < FRn; ++j)
                bfr[j] = *(const bf16x8*)&Bs[wn + 16 * j + lm][kh * 32 + lq * 8];
#pragma unroll
            for (int i = 0; i < FRm; ++i)
#pragma unroll
                for (int j = 0; j < FRn; ++j)
                    acc[i][j] = __builtin_amdgcn_mfma_f32_16x16x32_bf16(
                        af[i], bfr[j], acc[i][j], 0, 0, 0);
        }
        __syncthreads();
    }

    bf16* Cd = (MODE == 5) ? nullptr : Cb + (size_t)dir * Cstr;
#pragma unroll
    for (int i = 0; i < FRm; ++i) {
#pragma unroll
        for (int j = 0; j < FRn; ++j) {
            int col = bn + wn + 16 * j + lm;
            float bv = (MODE == 2) ? bias[col]
                     : (MODE == 5) ? 2.f * bias[col] : 0.f;
#pragma unroll
            for (int r = 0; r < 4; ++r) {
                int row = bm + wm + 16 * i + lq * 4 + r;
                float v = acc[i][j][r] + bv;
                size_t idx = (size_t)row * ldc + col;
                if (MODE == 0)      Cd[idx] = __float2bfloat16(v);
                else if (MODE == 2) Cd[idx] = __float2bfloat16(fmaxf(v, 0.f));
                else {
                    float m2 = __bfloat162float(mp[idx])
                             + __bfloat162float(mp[mpStr + idx]);
                    outp[idx] = v + m2;
                }
            }
        }
    }
}

// ---------------- zgate: yrow = silu(x(flip?) @ inw_z) * y2t^T ---------------
__global__ __launch_bounds__(256)
void zgate_k(const bf16* __restrict__ xbf, const bf16* __restrict__ inwT,
             const bf16* __restrict__ y2t_all, bf16* __restrict__ yrow_all)
{
    __shared__ __align__(16) bf16 As[64][40];
    __shared__ __align__(16) bf16 Bs[128][40];
    __shared__ __bf16 sy[64][130];
    const int tid = threadIdx.x;
    const int dir = blockIdx.z;
    const bf16* Bd = inwT + (size_t)dir * (2048 * 512) + (size_t)1024 * 512;
    const bf16* y2t = y2t_all + (size_t)dir * ((size_t)MROWS * EDIM);
    bf16* yrow = yrow_all + (size_t)dir * ((size_t)MROWS * EDIM);
    const int bm = blockIdx.y * 64, bn = blockIdx.x * 128;
    const int wave = tid >> 6, lane = tid & 63;
    const int wm = (wave >> 1) * 32, wn = (wave & 1) * 64;
    const int lm = lane & 15, lq = lane >> 4;
    f32x4 acc[2][4] = {};

    for (int k0 = 0; k0 < 512; k0 += 32) {
        {
            int row = tid >> 2, col = (tid & 3) * 8;
            int gm = bm + row;
            if (dir == 1) gm = (gm & ~(LD - 1)) + (LD - 1 - (gm & (LD - 1)));
            *(bf16x8*)&As[row][col] =
                *(const bf16x8*)(xbf + (size_t)gm * 512 + k0 + col);
        }
#pragma unroll
        for (int p = 0; p < 2; ++p) {
            int row = p * 64 + (tid >> 2), col = (tid & 3) * 8;
            *(bf16x8*)&Bs[row][col] =
                *(const bf16x8*)(Bd + (size_t)(bn + row) * 512 + k0 + col);
        }
        __syncthreads();
        bf16x8 af[2], bfr[4];
#pragma unroll
        for (int i = 0; i < 2; ++i)
            af[i] = *(const bf16x8*)&As[wm + 16 * i + lm][lq * 8];
#pragma unroll
        for (int j = 0; j < 4; ++j)
            bfr[j] = *(const bf16x8*)&Bs[wn + 16 * j + lm][lq * 8];
#pragma unroll
        for (int i = 0; i < 2; ++i)
#pragma unroll
            for (int j = 0; j < 4; ++j)
                acc[i][j] = __builtin_amdgcn_mfma_f32_16x16x32_bf16(
                    af[i], bfr[j], acc[i][j], 0, 0, 0);
        __syncthreads();
    }

    {
        const int b = bm >> 11, l0 = bm & (LD - 1);
        int e = tid >> 1, lh = (tid & 1) * 32;
        const bf16* yp = y2t + ((size_t)b * EDIM + bn + e) * LD + l0 + lh;
#pragma unroll
        for (int i = 0; i < 4; ++i) {
            bf16x8 v = *(const bf16x8*)(yp + i * 8);
#pragma unroll
            for (int j = 0; j < 8; ++j) sy[lh + i * 8 + j][e] = v[j];
        }
    }
    __syncthreads();
#pragma unroll
    for (int i = 0; i < 2; ++i) {
#pragma unroll
        for (int j = 0; j < 4; ++j) {
            int col = bn + wn + 16 * j + lm;
#pragma unroll
            for (int r = 0; r < 4; ++r) {
                int row = bm + wm + 16 * i + lq * 4 + r;
                float z = acc[i][j][r];
                float g = z * sig_(z);
                float y = (float)sy[(row - bm)][col - bn];
                yrow[(size_t)row * EDIM + col] = __float2bfloat16(g * y);
            }
        }
    }
}

// ---------------- conv(4)+bias+silu+transpose, dir-merged, vectorized --------
__global__ __launch_bounds__(256)
void conv2_k(const bf16* __restrict__ xs2,
             const float* __restrict__ cw_f, const float* __restrict__ cb_f,
             const float* __restrict__ cw_b, const float* __restrict__ cb_b,
             bf16* __restrict__ xct2)
{
    __shared__ float sxs[67][65];
    __shared__ float sout[64][65];
    const int tid = threadIdx.x;
    const int dir = blockIdx.z;
    const bf16* xs = xs2 + (size_t)dir * ((size_t)MROWS * EDIM);
    const float* w  = dir ? cw_b : cw_f;
    const float* cb = dir ? cb_b : cb_f;
    bf16* xct = xct2 + (size_t)dir * ((size_t)MROWS * EDIM);
    const int e0 = blockIdx.x * 64;
    const int bl0 = blockIdx.y * 64;
    const int lloc0 = bl0 & (LD - 1);
    const int b = bl0 >> 11;
    {
        int c8 = (tid & 7) * 8;
#pragma unroll
        for (int i = 0; i < 3; ++i) {
            int hr = i * 32 + (tid >> 3);
            if (hr < 67) {
                int lr = lloc0 + hr - 3;
                if (lr >= 0) {
                    bf16x8 v = *(const bf16x8*)(xs +
                        (size_t)(bl0 + hr - 3) * EDIM + e0 + c8);
#pragma unroll
                    for (int j = 0; j < 8; ++j) sxs[hr][c8 + j] = (float)v[j];
                } else {
#pragma unroll
                    for (int j = 0; j < 8; ++j) sxs[hr][c8 + j] = 0.f;
                }
            }
        }
    }
    __syncthreads();
    {
        int lr4 = tid >> 6, e = tid & 63;
        float w0 = w[(e0 + e) * 4 + 0], w1 = w[(e0 + e) * 4 + 1];
        float w2 = w[(e0 + e) * 4 + 2], w3 = w[(e0 + e) * 4 + 3];
        float cbv = cb[e0 + e];
#pragma unroll
        for (int i = 0; i < 16; ++i) {
            int lr = i * 4 + lr4;
            float acc = cbv;
            acc = fmaf(sxs[lr + 0][e], w0, acc);
            acc = fmaf(sxs[lr + 1][e], w1, acc);
            acc = fmaf(sxs[lr + 2][e], w2, acc);
            acc = fmaf(sxs[lr + 3][e], w3, acc);
            sout[e][lr] = acc * sig_(acc);
        }
    }
    __syncthreads();
    {
        int l8 = (tid & 7) * 8;
#pragma unroll
        for (int i = 0; i < 2; ++i) {
            int er = i * 32 + (tid >> 3);
            bf16x8 o;
#pragma unroll
            for (int j = 0; j < 8; ++j) o[j] = (__bf16)sout[er][l8 + j];
            *(bf16x8*)(xct + ((size_t)b * EDIM + e0 + er) * LD + lloc0 + l8) = o;
        }
    }
}

// ---------------- g2m: MFMA dbl = xc @ xproj (dt rows row-major) -------------
__global__ __launch_bounds__(256)
void g2m_k(const bf16* __restrict__ xct2, const bf16* __restrict__ xpT2,
           float* __restrict__ dblt2, float* __restrict__ dbldt2)
{
    __shared__ float As[64][33];            // [l][e] transposed, <=2-way banks
    __shared__ __align__(16) bf16 Bs[64][32];
    __shared__ float sC[32][65];            // n-rows 32..63 staging
    const int tid = threadIdx.x;
    const int dir = blockIdx.z;
    const bf16* xct = xct2 + (size_t)dir * ((size_t)MROWS * EDIM);
    const bf16* xpT = xpT2 + (size_t)dir * (64 * 1024);
    float* dblt = dblt2 + (size_t)dir * (2 * 64 * LD);
    float* dbldt = dbldt2 + (size_t)dir * (2 * 2048 * DTR);
    const int bm = blockIdx.y * 64;
    const int bB = bm >> 11, l0 = bm & (LD - 1);
    const int wave = tid >> 6, lane = tid & 63;
    const int wm = (wave >> 1) * 32, wn = (wave & 1) * 32;
    const int lm = lane & 15, lq = lane >> 4;
    const int er = tid >> 3, l8 = (tid & 7) * 8;   // A-stage coords
    f32x4 acc[2][2] = {};

    for (int k0 = 0; k0 < EDIM; k0 += 32) {
        glds16(xpT + (size_t)(wave * 16 + (lane >> 2)) * 1024 + k0 + (lane & 3) * 8,
               &Bs[wave * 16][0]);
        {
            bf16x8 v = *(const bf16x8*)(xct +
                ((size_t)bB * EDIM + k0 + er) * LD + l0 + l8);
#pragma unroll
            for (int j = 0; j < 8; ++j) As[l8 + j][er] = (float)v[j];
        }
        __syncthreads();
        bf16x8 af[2], bfr[2];
#pragma unroll
        for (int i = 0; i < 2; ++i) {
            int row = wm + 16 * i + lm;
#pragma unroll
            for (int j = 0; j < 8; ++j) af[i][j] = (__bf16)As[row][lq * 8 + j];
        }
#pragma unroll
        for (int j = 0; j < 2; ++j)
            bfr[j] = *(const bf16x8*)&Bs[wn + 16 * j + lm][lq * 8];
#pragma unroll
        for (int i = 0; i < 2; ++i)
#pragma unroll
            for (int j = 0; j < 2; ++j)
                acc[i][j] = __builtin_amdgcn_mfma_f32_16x16x32_bf16(
                    af[i], bfr[j], acc[i][j], 0, 0, 0);
        __syncthreads();
    }
    if (wn == 0) {
#pragma unroll
        for (int i = 0; i < 2; ++i)
#pragma unroll
            for (int j = 0; j < 2; ++j) {
                int col = 16 * j + lm;
#pragma unroll
                for (int r = 0; r < 4; ++r) {
                    int row = wm + 16 * i + lq * 4 + r;
                    dbldt[(size_t)(bB * 2048 + l0 + row) * DTR + col] =
                        acc[i][j][r];
                }
            }
    } else {
#pragma unroll
        for (int i = 0; i < 2; ++i)
#pragma unroll
            for (int j = 0; j < 2; ++j) {
                int col = 16 * j + lm;
#pragma unroll
                for (int r = 0; r < 4; ++r)
                    sC[col][wm + 16 * i + lq * 4 + r] = acc[i][j][r];
            }
    }
    __syncthreads();
    {
        int nr = tid >> 3, ll = (tid & 7) * 8;
        float4 v0 = *(const float4*)&sC[nr][ll];
        float4 v1 = *(const float4*)&sC[nr][ll + 4];
        float* d = dblt + (size_t)(bB * 64 + 32 + nr) * LD + l0 + ll;
        *(float4*)d = v0; *(float4*)(d + 4) = v1;
    }
}

// ---------------- g3m: MFMA dlt_t = softplus(dbldt @ dtw + b)^T --------------
__global__ __launch_bounds__(256)
void g3m_k(const float* __restrict__ dbldt2, const bf16* __restrict__ dtwT2,
           const float* __restrict__ dtb_f, const float* __restrict__ dtb_b,
           bf16* __restrict__ dltt2)
{
    __shared__ __align__(16) bf16 As[64][40];
    __shared__ __align__(16) bf16 Bs[64][32];
    __shared__ float sC[64][65];
    const int tid = threadIdx.x;
    const int dir = blockIdx.z;
    const float* Ap = dbldt2 + (size_t)dir * (2 * 2048 * DTR);
    const bf16* BT = dtwT2 + (size_t)dir * (1024 * DTR);
    const float* bias = dir ? dtb_b : dtb_f;
    bf16* dltt = dltt2 + (size_t)dir * ((size_t)MROWS * EDIM);
    const int bm = blockIdx.y * 64, bn = blockIdx.x * 64;
    const int bB = bm >> 11, l0 = bm & (LD - 1);
    const int wave = tid >> 6, lane = tid & 63;
    const int wm = (wave >> 1) * 32, wn = (wave & 1) * 32;
    const int lm = lane & 15, lq = lane >> 4;

    {
        int row = tid >> 2, c8 = (tid & 3) * 8;
        const float* p = Ap + (size_t)(bB * 2048 + l0 + row) * DTR + c8;
        float4 v0 = *(const float4*)p, v1 = *(const float4*)(p + 4);
        bf16x8 o;
        o[0]=(__bf16)v0.x; o[1]=(__bf16)v0.y; o[2]=(__bf16)v0.z; o[3]=(__bf16)v0.w;
        o[4]=(__bf16)v1.x; o[5]=(__bf16)v1.y; o[6]=(__bf16)v1.z; o[7]=(__bf16)v1.w;
        *(bf16x8*)&As[row][c8] = o;
    }
    glds16(BT + (size_t)(bn + wave * 16 + (lane >> 2)) * DTR + (lane & 3) * 8,
           &Bs[wave * 16][0]);
    __syncthreads();

    bf16x8 af[2], bfr[2];
#pragma unroll
    for (int i = 0; i < 2; ++i)
        af[i] = *(const bf16x8*)&As[wm + 16 * i + lm][lq * 8];
#pragma unroll
    for (int j = 0; j < 2; ++j)
        bfr[j] = *(const bf16x8*)&Bs[wn + 16 * j + lm][lq * 8];
    f32x4 acc[2][2] = {};
#pragma unroll
    for (int i = 0; i < 2; ++i)
#pragma unroll
        for (int j = 0; j < 2; ++j)
            acc[i][j] = __builtin_amdgcn_mfma_f32_16x16x32_bf16(
                af[i], bfr[j], acc[i][j], 0, 0, 0);

#pragma unroll
    for (int i = 0; i < 2; ++i)
#pragma unroll
        for (int j = 0; j < 2; ++j) {
            int col = wn + 16 * j + lm;
            float bv = bias[bn + col];
#pragma unroll
            for (int r = 0; r < 4; ++r) {
                int row = wm + 16 * i + lq * 4 + r;
                float v = acc[i][j][r] + bv;
                v = (v > 20.f) ? v : log1pf(__expf(v));
                sC[col][row] = v;
            }
        }
    __syncthreads();
    {
        int erow = tid >> 2, l16 = (tid & 3) * 16;
        bf16* d = dltt + ((size_t)bB * EDIM + bn + erow) * LD + l0 + l16;
#pragma unroll
        for (int h = 0; h < 2; ++h) {
            bf16x8 o;
#pragma unroll
            for (int j = 0; j < 8; ++j) o[j] = (__bf16)sC[erow][l16 + h * 8 + j];
            *(bf16x8*)(d + h * 8) = o;
        }
    }
}

// ---------------- scan9: parallel scan, n-loop unrolled x2 -------------------
// scan6's exact math; two independent states per iteration so their
// dependent shfl (KS) chains interleave and hide each other's DS latency.
// Barriers 16 -> 8. All sWp/sWs slots distinct across the loop -> race-free.
__global__ __launch_bounds__(256)
void scan9_k(bf16* __restrict__ xct2, const bf16* __restrict__ dltt2,
             const float* __restrict__ dblt2,
             const float* __restrict__ alog_f, const float* __restrict__ alog_b,
             const float* __restrict__ dp_f, const float* __restrict__ dp_b)
{
    __shared__ float sA[NST];
    __shared__ float sWp[NST][4];
    __shared__ float sWs[NST][4];
    const int gid = blockIdx.x;                 // 0..4095
    const int dir = gid >> 11;
    const int bb  = (gid >> 10) & 1;
    const int e   = gid & (EDIM - 1);
    const float* A_log = dir ? alog_b : alog_f;
    const float* Dp    = dir ? dp_b   : dp_f;
    bf16* xct = xct2 + (size_t)dir * ((size_t)MROWS * EDIM);
    const bf16* dltt = dltt2 + (size_t)dir * ((size_t)MROWS * EDIM);
    const float* bt = dblt2 + (size_t)dir * (2 * 64 * LD) + (size_t)bb * 64 * LD;
    const int tid = threadIdx.x;
    const int wave = tid >> 6, lane = tid & 63;
    const size_t baset = ((size_t)bb * EDIM + e) * LD;
    const int l0 = tid * 8;

    if (tid < NST) sA[tid] = -__expf(A_log[e * NST + tid]);

    float xv[8], dv[8], dx[8];
    {
        bf16x8 xr = *(const bf16x8*)(xct + baset + l0);
        bf16x8 dr = *(const bf16x8*)(dltt + baset + l0);
#pragma unroll
        for (int j = 0; j < 8; ++j) { xv[j] = (float)xr[j]; dv[j] = (float)dr[j]; }
    }
#pragma unroll
    for (int j = 0; j < 8; ++j) dx[j] = dv[j] * xv[j];
    __syncthreads();

    float y[8] = {};
    for (int n = 0; n < NST; n += 2) {
        const float An0 = sA[n], An1 = sA[n + 1];
        const float* Bp0 = bt + (size_t)(DTR + n) * LD + l0;
        const float* Cp0 = bt + (size_t)(DTR + NST + n) * LD + l0;
        const float* Bp1 = bt + (size_t)(DTR + n + 1) * LD + l0;
        const float* Cp1 = bt + (size_t)(DTR + NST + n + 1) * LD + l0;
        float4 b00 = *(const float4*)Bp0, b01 = *(const float4*)(Bp0 + 4);
        float4 c00 = *(const float4*)Cp0, c01 = *(const float4*)(Cp0 + 4);
        float4 b10 = *(const float4*)Bp1, b11 = *(const float4*)(Bp1 + 4);
        float4 c10 = *(const float4*)Cp1, c11 = *(const float4*)(Cp1 + 4);
        float Br0[8] = {b00.x,b00.y,b00.z,b00.w, b01.x,b01.y,b01.z,b01.w};
        float Cr0[8] = {c00.x,c00.y,c00.z,c00.w, c01.x,c01.y,c01.z,c01.w};
        float Br1[8] = {b10.x,b10.y,b10.z,b10.w, b11.x,b11.y,b11.z,b11.w};
        float Cr1[8] = {c10.x,c10.y,c10.z,c10.w, c11.x,c11.y,c11.z,c11.w};

        // two independent walks (compiler interleaves the exp streams)
        float S0[8], P0[8], S1[8], P1[8];
        float h0 = 0.f, pr0 = 1.f, h1 = 0.f, pr1 = 1.f;
#pragma unroll
        for (int l = 0; l < 8; ++l) {
            float a0 = __expf(dv[l] * An0);
            float a1 = __expf(dv[l] * An1);
            pr0 *= a0; pr1 *= a1;
            h0 = fmaf(a0, h0, dx[l] * Br0[l]);
            h1 = fmaf(a1, h1, dx[l] * Br1[l]);
            P0[l] = pr0; S0[l] = h0;
            P1[l] = pr1; S1[l] = h1;
        }

        // two interleaved Kogge-Stone inclusive affine scans
        float p0 = pr0, s0 = h0, p1 = pr1, s1 = h1;
#pragma unroll
        for (int d = 1; d < 64; d <<= 1) {
            float pp0 = __shfl_up(p0, d, 64);
            float sp0 = __shfl_up(s0, d, 64);
            float pp1 = __shfl_up(p1, d, 64);
            float sp1 = __shfl_up(s1, d, 64);
            if (lane >= d) {
                s0 = fmaf(sp0, p0, s0); p0 *= pp0;
                s1 = fmaf(sp1, p1, s1); p1 *= pp1;
            }
        }
        if (lane == 63) {
            sWp[n][wave] = p0;     sWs[n][wave] = s0;
            sWp[n + 1][wave] = p1; sWs[n + 1][wave] = s1;
        }
        __syncthreads();
        float Hoff0 = 0.f, Hoff1 = 0.f;
#pragma unroll
        for (int w = 0; w < 3; ++w)
            if (w < wave) {
                Hoff0 = fmaf(sWp[n][w], Hoff0, sWs[n][w]);
                Hoff1 = fmaf(sWp[n + 1][w], Hoff1, sWs[n + 1][w]);
            }
        float pprev0 = __shfl_up(p0, 1, 64);
        float sprev0 = __shfl_up(s0, 1, 64);
        float pprev1 = __shfl_up(p1, 1, 64);
        float sprev1 = __shfl_up(s1, 1, 64);
        float H0 = (lane == 0) ? Hoff0 : fmaf(pprev0, Hoff0, sprev0);
        float H1 = (lane == 0) ? Hoff1 : fmaf(pprev1, Hoff1, sprev1);

#pragma unroll
        for (int l = 0; l < 8; ++l) {
            y[l] = fmaf(Cr0[l], fmaf(P0[l], H0, S0[l]), y[l]);
            y[l] = fmaf(Cr1[l], fmaf(P1[l], H1, S1[l]), y[l]);
        }
    }

    const float Dv = Dp[e];
    bf16x8 o;
#pragma unroll
    for (int l = 0; l < 8; ++l) o[l] = (__bf16)fmaf(xv[l], Dv, y[l]);
    *(bf16x8*)(xct + baset + l0) = o;
}

// ---------------- layernorm (bf16 in-place), dir0 rows only ------------------
__global__ __launch_bounds__(256)
void ln_k(bf16* __restrict__ m, const float* __restrict__ gg,
          const float* __restrict__ bb)
{
    int row = (blockIdx.x * 256 + threadIdx.x) >> 6;
    int lane = threadIdx.x & 63;
    bf16* r = m + (size_t)row * DMODEL;
    float v[8], s = 0.f, s2 = 0.f;
#pragma unroll
    for (int i = 0; i < 8; ++i) {
        v[i] = __bfloat162float(r[lane + 64 * i]);
        s += v[i]; s2 = fmaf(v[i], v[i], s2);
    }
#pragma unroll
    for (int off = 32; off >= 1; off >>= 1) {
        s  += __shfl_xor(s, off, 64);
        s2 += __shfl_xor(s2, off, 64);
    }
    float mu = s * (1.f / DMODEL);
    float var = s2 * (1.f / DMODEL) - mu * mu;
    float inv = rsqrtf(var + 1e-5f);
#pragma unroll
    for (int i = 0; i < 8; ++i)
        r[lane + 64 * i] = __float2bfloat16(
            (v[i] - mu) * inv * gg[lane + 64 * i] + bb[lane + 64 * i]);
}

__global__ void sentinel_k(float* __restrict__ o)
{
    int i = blockIdx.x * 256 + threadIdx.x;
    o[i] = 100.0f;
}

extern "C" void kernel_launch(void* const* d_in, const int* in_sizes, int n_in,
                              void* d_out, int out_size, void* d_ws, size_t ws_size,
                              hipStream_t stream)
{
    const float* x    = (const float*)d_in[0];
    const float* n1g  = (const float*)d_in[19];
    const float* n1b  = (const float*)d_in[20];
    const float* fw1  = (const float*)d_in[23];
    const float* fb1  = (const float*)d_in[24];
    const float* fw2  = (const float*)d_in[25];
    const float* fb2  = (const float*)d_in[26];
    float* out = (float*)d_out;

    const size_t MiB = 1024 * 1024;
    const size_t SZ_DM = (size_t)MROWS * DMODEL;
    if (ws_size < 49 * MiB) {
        sentinel_k<<<dim3(SZ_DM / 256), dim3(256), 0, stream>>>(out);
        return;
    }

    // ---- 48.4 MiB layout ----
    char* base = (char*)d_ws;
    bf16* fw1T  = (bf16*)base;                 // [1024][512]        1 MiB
    bf16* fw2T  = (bf16*)(base + 1 * MiB);     // [512][1024]        1 MiB
    bf16* outwT = (bf16*)(base + 2 * MiB);     // [2][512][1024]     2 MiB
    bf16* inwT  = (bf16*)(base + 4 * MiB);     // [2][2048][512]     4 MiB
    bf16* xbf   = (bf16*)(base + 8 * MiB);     // [4096][512]        4 MiB
    char* RA    = base + 12 * MiB;             // 16 MiB: xs2 -> dltt2 -> yrow2 -> ffh2
    bf16* xs2   = (bf16*)RA;                   // [2][4096][1024]
    bf16* dltt2 = (bf16*)RA;
    bf16* yrow2 = (bf16*)RA;
    bf16* ffh2  = (bf16*)RA;
    char* RB    = base + 28 * MiB;             // 16 MiB: xct2 -> mbf2
    bf16* xct2  = (bf16*)RB;                   // [2][2][1024][2048]
    bf16* mbf2  = (bf16*)RB;                   // [2][4096][512]
    float* dblt2 = (float*)(base + 44 * MiB);  // [2][2][64][2048]   2 MiB (rows 32..63 used)
    float* dbldt2 = (float*)(base + 46 * MiB); // [2][2][2048][32]   2 MiB
    bf16* xpT2  = (bf16*)(base + 48 * MiB);               // [2][64][1024]  256 KiB
    bf16* dtwT2 = (bf16*)(base + 48 * MiB + 256 * 1024);  // [2][1024][32]  128 KiB

    const float* inw_f  = (const float*)d_in[1];
    const float* cw_f   = (const float*)d_in[2];
    const float* cb_f   = (const float*)d_in[3];
    const float* xp_f   = (const float*)d_in[4];
    const float* dtw_f  = (const float*)d_in[5];
    const float* dtb_f  = (const float*)d_in[6];
    const float* alog_f = (const float*)d_in[7];
    const float* dp_f   = (const float*)d_in[8];
    const float* outw_f = (const float*)d_in[9];
    const float* inw_b  = (const float*)d_in[10];
    const float* cw_b   = (const float*)d_in[11];
    const float* cb_b   = (const float*)d_in[12];
    const float* xp_b   = (const float*)d_in[13];
    const float* dtw_b  = (const float*)d_in[14];
    const float* dtb_b  = (const float*)d_in[15];
    const float* alog_b = (const float*)d_in[16];
    const float* dp_b   = (const float*)d_in[17];
    const float* outw_b = (const float*)d_in[18];

    dim3 blk(256);
    const size_t U = (size_t)MROWS * EDIM;   // 4,194,304 elems

    // 1. prep: all transposes + xconv
    prep_k<<<dim3(6336), blk, 0, stream>>>(x, xbf, inw_f, inw_b, inwT,
                                           outw_f, outw_b, outwT,
                                           fw1, fw1T, fw2, fw2T,
                                           xp_f, xp_b, xpT2,
                                           dtw_f, dtw_b, dtwT2);
    // 2. G1: xs2[dir] = x(flip d1) @ in_w[:, :1024]   M=4096 N=1024 K=512
    bgemm3_k<128, 0, true, false><<<dim3(8, 32, 2), blk, 0, stream>>>(
        xbf, 0, DMODEL, inwT, (size_t)2048 * 512, DMODEL, nullptr,
        xs2, U, EDIM, nullptr, 0, nullptr, DMODEL);
    // 3. conv + silu + transpose
    conv2_k<<<dim3(16, 64, 2), blk, 0, stream>>>(xs2, cw_f, cb_f, cw_b, cb_b, xct2);
    // 4. G2 (MFMA): dblt rows 32..63 + dbldt row-major
    g2m_k<<<dim3(1, 64, 2), blk, 0, stream>>>(xct2, xpT2, dblt2, dbldt2);
    // 5. G3 (MFMA): dltt2 (over dead xs2)
    g3m_k<<<dim3(16, 64, 2), blk, 0, stream>>>(dbldt2, dtwT2, dtb_f, dtb_b, dltt2);
    // 6. scan (in-place over xct2) — x2-unrolled parallel scan
    scan9_k<<<dim3(4096), blk, 0, stream>>>(xct2, dltt2, dblt2,
                                            alog_f, alog_b, dp_f, dp_b);
    // 7. zgate: yrow2 = silu(x @ inw_z) * y  (writes over dead dltt2)
    zgate_k<<<dim3(8, 64, 2), blk, 0, stream>>>(xbf, inwT, xct2, yrow2);
    // 8. G4: mbf2[dir] = y @ out_w   M=4096 N=512 K=1024
    bgemm3_k<64, 0, false, false><<<dim3(8, 32, 2), blk, 0, stream>>>(
        yrow2, U, EDIM, outwT, (size_t)512 * 1024, EDIM, nullptr,
        mbf2, SZ_DM, DMODEL, nullptr, 0, nullptr, EDIM);
    // 9. LN on dir0 half of mbf2 (in place)
    ln_k<<<dim3(MROWS / 4), blk, 0, stream>>>(mbf2, n1g, n1b);
    // 10. G5: ffh2[dir] = relu(m @ fw1 + fb1)   M=4096 N=1024 K=512
    bgemm3_k<128, 2, false, false><<<dim3(8, 32, 2), blk, 0, stream>>>(
        mbf2, SZ_DM, DMODEL, fw1T, 0, DMODEL, fb1,
        ffh2, U, DFF, nullptr, 0, nullptr, DMODEL);
    // 11. G6 fused (concat-K): out = ffh_f@fw2 + ffh_b@fw2 + 2*fb2 + m_f + m_b
    bgemm3_k<64, 5, false, true><<<dim3(8, 32, 1), blk, 0, stream>>>(
        ffh2, U, DFF, fw2T, 0, DFF, fb2,
        nullptr, 0, DMODEL, mbf2, SZ_DM, out, 2 * DFF);
}

// Round 7
// 369.781 us; speedup vs baseline: 1.0016x; 1.0016x over previous
//
#include <hip/hip_runtime.h>
#include <hip/hip_bf16.h>
#include <math.h>

// BiMambaEncoderLayer: B=2, L=2048, D_MODEL=512, ED=1024, N=16, DCONV=4,
// DT_RANK=32, D_FF=1024. f32 in/out.
// Round-22:
//  (a) REVERT scan -> scan6 verbatim (66.2us known-good). Three scan
//      rewrites (scan7/8/9) all regressed: every variant that adds VGPR
//      or removes issue-work loses more occupancy than it gains. scan6
//      (40 VGPR / 54% occ / 75% VALUBusy) is the balanced local optimum.
//  (b) bgemm3: T3 minimum-2-phase pipeline. BK=32 double-buffered LDS
//      (2x16KB = same 32KB footprint as old BK=64 single-buffer), one
//      barrier per K-step (was 2), STAGE(t+1) issued BEFORE COMPUTE(t)
//      so global_load_lds flies under the 16 MFMA. Guide: +10% measured
//      same-probe (m248v2).
//  11 dispatches, 48.4 MiB workspace.

#define BD 2
#define LD 2048
#define DMODEL 512
#define EDIM 1024
#define NST 16
#define DTR 32
#define DFF 1024
#define MROWS (BD*LD)   // 4096

typedef __hip_bfloat16 bf16;
typedef __bf16 bf16x8 __attribute__((ext_vector_type(8)));
typedef __bf16 bf16x4 __attribute__((ext_vector_type(4)));
typedef float  f32x4  __attribute__((ext_vector_type(4)));

__device__ __forceinline__ float sig_(float x) { return 1.f / (1.f + __expf(-x)); }

// async 16B global->LDS (wave-uniform LDS base, per-lane global addr)
__device__ __forceinline__ void glds16(const void* g, void* l)
{
    __builtin_amdgcn_global_load_lds(
        (const __attribute__((address_space(1))) void*)g,
        (__attribute__((address_space(3))) void*)l, 16, 0, 0);
}

// ---------------- prep: all weight transposes + x->bf16, one dispatch --------
// [0,2048) xconv | [2048,4096) inwT | [4096,5120) outwT | [5120,5632) fw1T |
// [5632,6144) fw2T | [6144,6272) xpT | [6272,6336) dtwT
__global__ __launch_bounds__(256)
void prep_k(const float* __restrict__ x, bf16* __restrict__ xbf,
            const float* __restrict__ inw_f, const float* __restrict__ inw_b,
            bf16* __restrict__ inwT,
            const float* __restrict__ outw_f, const float* __restrict__ outw_b,
            bf16* __restrict__ outwT,
            const float* __restrict__ fw1, bf16* __restrict__ fw1T,
            const float* __restrict__ fw2, bf16* __restrict__ fw2T,
            const float* __restrict__ xp_f, const float* __restrict__ xp_b,
            bf16* __restrict__ xpT,
            const float* __restrict__ dtw_f, const float* __restrict__ dtw_b,
            bf16* __restrict__ dtwT)
{
    const int bid = blockIdx.x, tid = threadIdx.x;
    if (bid < 2048) {
        size_t i = (size_t)bid * 1024 + tid * 4;
        float4 v = *(const float4*)(x + i);
        bf16* o = xbf + i;
        o[0] = __float2bfloat16(v.x); o[1] = __float2bfloat16(v.y);
        o[2] = __float2bfloat16(v.z); o[3] = __float2bfloat16(v.w);
        return;
    }
    const float* W; bf16* WT; int R, C, cx, ry;
    if (bid < 4096) {
        int d = (bid - 2048) >> 10, t = (bid - 2048) & 1023;
        W = d ? inw_b : inw_f; WT = inwT + (size_t)d * 2048 * 512;
        R = 512; C = 2048; cx = t & 63; ry = t >> 6;
    } else if (bid < 5120) {
        int d = (bid - 4096) >> 9, t = (bid - 4096) & 511;
        W = d ? outw_b : outw_f; WT = outwT + (size_t)d * 512 * 1024;
        R = 1024; C = 512; cx = t & 15; ry = t >> 4;
    } else if (bid < 5632) {
        int t = bid - 5120; W = fw1; WT = fw1T; R = 512; C = 1024;
        cx = t & 31; ry = t >> 5;
    } else if (bid < 6144) {
        int t = bid - 5632; W = fw2; WT = fw2T; R = 1024; C = 512;
        cx = t & 15; ry = t >> 4;
    } else if (bid < 6272) {
        int d = (bid - 6144) >> 6, t = (bid - 6144) & 63;
        W = d ? xp_b : xp_f; WT = xpT + (size_t)d * 64 * 1024;
        R = 1024; C = 64; cx = t & 1; ry = t >> 1;
    } else {
        int d = (bid - 6272) >> 5, t = (bid - 6272) & 31;
        W = d ? dtw_b : dtw_f; WT = dtwT + (size_t)d * 1024 * DTR;
        R = 32; C = 1024; cx = t; ry = 0;
    }
    __shared__ float tt[32][33];
    const int c0 = cx * 32, r0 = ry * 32;
    const int col = tid & 31, rr = tid >> 5;
#pragma unroll
    for (int p = 0; p < 4; ++p)
        tt[p * 8 + rr][col] = W[(size_t)(r0 + p * 8 + rr) * C + c0 + col];
    __syncthreads();
#pragma unroll
    for (int p = 0; p < 4; ++p)
        WT[(size_t)(c0 + p * 8 + rr) * R + r0 + col] =
            __float2bfloat16(tt[col][p * 8 + rr]);
}

// ---------------- bgemm3: 128xBN MFMA GEMM, BK=32, 2-phase dbuf -------------
// STAGE(t+1) issued before COMPUTE(t); one __syncthreads per K-step (drains
// vmcnt for the prefetch AND lgkm for the ds_reads). LDS 2 buffers.
template<int BN, int MODE, bool FLIPD1, bool CATK>
__global__ __launch_bounds__(256)
void bgemm3_k(const bf16* __restrict__ A, size_t Astr, int lda,
              const bf16* __restrict__ BT, size_t Bstr, int ldb,
              const float* __restrict__ bias,
              bf16* __restrict__ Cb, size_t Cstr, int ldc,
              const bf16* __restrict__ mp, size_t mpStr,
              float* __restrict__ outp, int K)
{
    constexpr int BM = 128, BK = 32;
    constexpr int FRm = 4, FRn = BN / 32;
    constexpr int KH = DFF;   // concat-K half length (1024)
    __shared__ __align__(16) bf16 As[2][BM][BK];
    __shared__ __align__(16) bf16 Bs[2][BN][BK];
    const int tid = threadIdx.x;
    const int dir = blockIdx.z;
    const bool flip = FLIPD1 && (dir == 1);
    const bf16* Ad = A + (CATK ? (size_t)0 : (size_t)dir * Astr);
    const bf16* Bd = BT + (size_t)dir * Bstr;
    const int bm = blockIdx.y * BM, bn = blockIdx.x * BN;
    const int wave = tid >> 6, lane = tid & 63;
    const int wm = (wave >> 1) * 64, wn = (wave & 1) * (BN / 2);
    const int lm = lane & 15, lq = lane >> 4;
    const int lrow = lane >> 2, lcol = (lane & 3) * 8;  // 16 rows x 64B / wave
    f32x4 acc[FRm][FRn] = {};

    auto STAGE = [&](int buf, int k0) {
        const bf16* Ab = Ad;
        int ka = k0;
        if (CATK && k0 >= KH) { Ab = A + Astr; ka = k0 - KH; }
        const int kb = CATK ? (k0 & (KH - 1)) : k0;
#pragma unroll
        for (int c = 0; c < 2; ++c) {
            int row = c * 64 + wave * 16 + lrow;
            int gm = bm + row;
            if (flip) gm = (gm & ~(LD - 1)) + (LD - 1 - (gm & (LD - 1)));
            glds16(Ab + (size_t)gm * lda + ka + lcol,
                   &As[buf][c * 64 + wave * 16][0]);
        }
#pragma unroll
        for (int c = 0; c < BN / 64; ++c) {
            int row = c * 64 + wave * 16 + lrow;
            glds16(Bd + (size_t)(bn + row) * ldb + kb + lcol,
                   &Bs[buf][c * 64 + wave * 16][0]);
        }
    };
    auto COMPUTE = [&](int buf) {
        bf16x8 af[FRm], bfr[FRn];
#pragma unroll
        for (int i = 0; i < FRm; ++i)
            af[i] = *(const bf16x8*)&As[buf][wm + 16 * i + lm][lq * 8];
#pragma unroll
        for (int j = 0; j < FRn; ++j)
            bfr[j] = *(const bf16x8*)&Bs[buf][wn + 16 * j + lm][lq * 8];
#pragma unroll
        for (int i = 0; i < FRm; ++i)
#pragma unroll
            for (int j = 0; j < FRn; ++j)
                acc[i][j] = __builtin_amdgcn_mfma_f32_16x16x32_bf16(
                    af[i], bfr[j], acc[i][j], 0, 0, 0);
    };

    STAGE(0, 0);
    __syncthreads();
    int cur = 0;
    for (int k0 = BK; k0 < K; k0 += BK) {
        STAGE(cur ^ 1, k0);   // prefetch next tile (flies under the MFMA)
        COMPUTE(cur);
        __syncthreads();      // drains prefetch vmcnt + our lgkm reads
        cur ^= 1;
    }
    COMPUTE(cur);

    bf16* Cd = (MODE == 5) ? nullptr : Cb + (size_t)dir * Cstr;
#pragma unroll
    for (int i = 0; i < FRm; ++i) {
#pragma unroll
        for (int j = 0; j < FRn; ++j) {
            int col = bn + wn + 16 * j + lm;
            float bv = (MODE == 2) ? bias[col]
                     : (MODE == 5) ? 2.f * bias[col] : 0.f;
#pragma unroll
            for (int r = 0; r < 4; ++r) {
                int row = bm + wm + 16 * i + lq * 4 + r;
                float v = acc[i][j][r] + bv;
                size_t idx = (size_t)row * ldc + col;
                if (MODE == 0)      Cd[idx] = __float2bfloat16(v);
                else if (MODE == 2) Cd[idx] = __float2bfloat16(fmaxf(v, 0.f));
                else {
                    float m2 = __bfloat162float(mp[idx])
                             + __bfloat162float(mp[mpStr + idx]);
                    outp[idx] = v + m2;
                }
            }
        }
    }
}

// ---------------- zgate: yrow = silu(x(flip?) @ inw_z) * y2t^T ---------------
__global__ __launch_bounds__(256)
void zgate_k(const bf16* __restrict__ xbf, const bf16* __restrict__ inwT,
             const bf16* __restrict__ y2t_all, bf16* __restrict__ yrow_all)
{
    __shared__ __align__(16) bf16 As[64][40];
    __shared__ __align__(16) bf16 Bs[128][40];
    __shared__ __bf16 sy[64][130];
    const int tid = threadIdx.x;
    const int dir = blockIdx.z;
    const bf16* Bd = inwT + (size_t)dir * (2048 * 512) + (size_t)1024 * 512;
    const bf16* y2t = y2t_all + (size_t)dir * ((size_t)MROWS * EDIM);
    bf16* yrow = yrow_all + (size_t)dir * ((size_t)MROWS * EDIM);
    const int bm = blockIdx.y * 64, bn = blockIdx.x * 128;
    const int wave = tid >> 6, lane = tid & 63;
    const int wm = (wave >> 1) * 32, wn = (wave & 1) * 64;
    const int lm = lane & 15, lq = lane >> 4;
    f32x4 acc[2][4] = {};

    for (int k0 = 0; k0 < 512; k0 += 32) {
        {
            int row = tid >> 2, col = (tid & 3) * 8;
            int gm = bm + row;
            if (dir == 1) gm = (gm & ~(LD - 1)) + (LD - 1 - (gm & (LD - 1)));
            *(bf16x8*)&As[row][col] =
                *(const bf16x8*)(xbf + (size_t)gm * 512 + k0 + col);
        }
#pragma unroll
        for (int p = 0; p < 2; ++p) {
            int row = p * 64 + (tid >> 2), col = (tid & 3) * 8;
            *(bf16x8*)&Bs[row][col] =
                *(const bf16x8*)(Bd + (size_t)(bn + row) * 512 + k0 + col);
        }
        __syncthreads();
        bf16x8 af[2], bfr[4];
#pragma unroll
        for (int i = 0; i < 2; ++i)
            af[i] = *(const bf16x8*)&As[wm + 16 * i + lm][lq * 8];
#pragma unroll
        for (int j = 0; j < 4; ++j)
            bfr[j] = *(const bf16x8*)&Bs[wn + 16 * j + lm][lq * 8];
#pragma unroll
        for (int i = 0; i < 2; ++i)
#pragma unroll
            for (int j = 0; j < 4; ++j)
                acc[i][j] = __builtin_amdgcn_mfma_f32_16x16x32_bf16(
                    af[i], bfr[j], acc[i][j], 0, 0, 0);
        __syncthreads();
    }

    {
        const int b = bm >> 11, l0 = bm & (LD - 1);
        int e = tid >> 1, lh = (tid & 1) * 32;
        const bf16* yp = y2t + ((size_t)b * EDIM + bn + e) * LD + l0 + lh;
#pragma unroll
        for (int i = 0; i < 4; ++i) {
            bf16x8 v = *(const bf16x8*)(yp + i * 8);
#pragma unroll
            for (int j = 0; j < 8; ++j) sy[lh + i * 8 + j][e] = v[j];
        }
    }
    __syncthreads();
#pragma unroll
    for (int i = 0; i < 2; ++i) {
#pragma unroll
        for (int j = 0; j < 4; ++j) {
            int col = bn + wn + 16 * j + lm;
#pragma unroll
            for (int r = 0; r < 4; ++r) {
                int row = bm + wm + 16 * i + lq * 4 + r;
                float z = acc[i][j][r];
                float g = z * sig_(z);
                float y = (float)sy[(row - bm)][col - bn];
                yrow[(size_t)row * EDIM + col] = __float2bfloat16(g * y);
            }
        }
    }
}

// ---------------- conv(4)+bias+silu+transpose, dir-merged, vectorized --------
__global__ __launch_bounds__(256)
void conv2_k(const bf16* __restrict__ xs2,
             const float* __restrict__ cw_f, const float* __restrict__ cb_f,
             const float* __restrict__ cw_b, const float* __restrict__ cb_b,
             bf16* __restrict__ xct2)
{
    __shared__ float sxs[67][65];
    __shared__ float sout[64][65];
    const int tid = threadIdx.x;
    const int dir = blockIdx.z;
    const bf16* xs = xs2 + (size_t)dir * ((size_t)MROWS * EDIM);
    const float* w  = dir ? cw_b : cw_f;
    const float* cb = dir ? cb_b : cb_f;
    bf16* xct = xct2 + (size_t)dir * ((size_t)MROWS * EDIM);
    const int e0 = blockIdx.x * 64;
    const int bl0 = blockIdx.y * 64;
    const int lloc0 = bl0 & (LD - 1);
    const int b = bl0 >> 11;
    {
        int c8 = (tid & 7) * 8;
#pragma unroll
        for (int i = 0; i < 3; ++i) {
            int hr = i * 32 + (tid >> 3);
            if (hr < 67) {
                int lr = lloc0 + hr - 3;
                if (lr >= 0) {
                    bf16x8 v = *(const bf16x8*)(xs +
                        (size_t)(bl0 + hr - 3) * EDIM + e0 + c8);
#pragma unroll
                    for (int j = 0; j < 8; ++j) sxs[hr][c8 + j] = (float)v[j];
                } else {
#pragma unroll
                    for (int j = 0; j < 8; ++j) sxs[hr][c8 + j] = 0.f;
                }
            }
        }
    }
    __syncthreads();
    {
        int lr4 = tid >> 6, e = tid & 63;
        float w0 = w[(e0 + e) * 4 + 0], w1 = w[(e0 + e) * 4 + 1];
        float w2 = w[(e0 + e) * 4 + 2], w3 = w[(e0 + e) * 4 + 3];
        float cbv = cb[e0 + e];
#pragma unroll
        for (int i = 0; i < 16; ++i) {
            int lr = i * 4 + lr4;
            float acc = cbv;
            acc = fmaf(sxs[lr + 0][e], w0, acc);
            acc = fmaf(sxs[lr + 1][e], w1, acc);
            acc = fmaf(sxs[lr + 2][e], w2, acc);
            acc = fmaf(sxs[lr + 3][e], w3, acc);
            sout[e][lr] = acc * sig_(acc);
        }
    }
    __syncthreads();
    {
        int l8 = (tid & 7) * 8;
#pragma unroll
        for (int i = 0; i < 2; ++i) {
            int er = i * 32 + (tid >> 3);
            bf16x8 o;
#pragma unroll
            for (int j = 0; j < 8; ++j) o[j] = (__bf16)sout[er][l8 + j];
            *(bf16x8*)(xct + ((size_t)b * EDIM + e0 + er) * LD + lloc0 + l8) = o;
        }
    }
}

// ---------------- g2m: MFMA dbl = xc @ xproj (dt rows row-major) -------------
__global__ __launch_bounds__(256)
void g2m_k(const bf16* __restrict__ xct2, const bf16* __restrict__ xpT2,
           float* __restrict__ dblt2, float* __restrict__ dbldt2)
{
    __shared__ float As[64][33];            // [l][e] transposed, <=2-way banks
    __shared__ __align__(16) bf16 Bs[64][32];
    __shared__ float sC[32][65];            // n-rows 32..63 staging
    const int tid = threadIdx.x;
    const int dir = blockIdx.z;
    const bf16* xct = xct2 + (size_t)dir * ((size_t)MROWS * EDIM);
    const bf16* xpT = xpT2 + (size_t)dir * (64 * 1024);
    float* dblt = dblt2 + (size_t)dir * (2 * 64 * LD);
    float* dbldt = dbldt2 + (size_t)dir * (2 * 2048 * DTR);
    const int bm = blockIdx.y * 64;
    const int bB = bm >> 11, l0 = bm & (LD - 1);
    const int wave = tid >> 6, lane = tid & 63;
    const int wm = (wave >> 1) * 32, wn = (wave & 1) * 32;
    const int lm = lane & 15, lq = lane >> 4;
    const int er = tid >> 3, l8 = (tid & 7) * 8;   // A-stage coords
    f32x4 acc[2][2] = {};

    for (int k0 = 0; k0 < EDIM; k0 += 32) {
        glds16(xpT + (size_t)(wave * 16 + (lane >> 2)) * 1024 + k0 + (lane & 3) * 8,
               &Bs[wave * 16][0]);
        {
            bf16x8 v = *(const bf16x8*)(xct +
                ((size_t)bB * EDIM + k0 + er) * LD + l0 + l8);
#pragma unroll
            for (int j = 0; j < 8; ++j) As[l8 + j][er] = (float)v[j];
        }
        __syncthreads();
        bf16x8 af[2], bfr[2];
#pragma unroll
        for (int i = 0; i < 2; ++i) {
            int row = wm + 16 * i + lm;
#pragma unroll
            for (int j = 0; j < 8; ++j) af[i][j] = (__bf16)As[row][lq * 8 + j];
        }
#pragma unroll
        for (int j = 0; j < 2; ++j)
            bfr[j] = *(const bf16x8*)&Bs[wn + 16 * j + lm][lq * 8];
#pragma unroll
        for (int i = 0; i < 2; ++i)
#pragma unroll
            for (int j = 0; j < 2; ++j)
                acc[i][j] = __builtin_amdgcn_mfma_f32_16x16x32_bf16(
                    af[i], bfr[j], acc[i][j], 0, 0, 0);
        __syncthreads();
    }
    if (wn == 0) {
#pragma unroll
        for (int i = 0; i < 2; ++i)
#pragma unroll
            for (int j = 0; j < 2; ++j) {
                int col = 16 * j + lm;
#pragma unroll
                for (int r = 0; r < 4; ++r) {
                    int row = wm + 16 * i + lq * 4 + r;
                    dbldt[(size_t)(bB * 2048 + l0 + row) * DTR + col] =
                        acc[i][j][r];
                }
            }
    } else {
#pragma unroll
        for (int i = 0; i < 2; ++i)
#pragma unroll
            for (int j = 0; j < 2; ++j) {
                int col = 16 * j + lm;
#pragma unroll
                for (int r = 0; r < 4; ++r)
                    sC[col][wm + 16 * i + lq * 4 + r] = acc[i][j][r];
            }
    }
    __syncthreads();
    {
        int nr = tid >> 3, ll = (tid & 7) * 8;
        float4 v0 = *(const float4*)&sC[nr][ll];
        float4 v1 = *(const float4*)&sC[nr][ll + 4];
        float* d = dblt + (size_t)(bB * 64 + 32 + nr) * LD + l0 + ll;
        *(float4*)d = v0; *(float4*)(d + 4) = v1;
    }
}

// ---------------- g3m: MFMA dlt_t = softplus(dbldt @ dtw + b)^T --------------
__global__ __launch_bounds__(256)
void g3m_k(const float* __restrict__ dbldt2, const bf16* __restrict__ dtwT2,
           const float* __restrict__ dtb_f, const float* __restrict__ dtb_b,
           bf16* __restrict__ dltt2)
{
    __shared__ __align__(16) bf16 As[64][40];
    __shared__ __align__(16) bf16 Bs[64][32];
    __shared__ float sC[64][65];
    const int tid = threadIdx.x;
    const int dir = blockIdx.z;
    const float* Ap = dbldt2 + (size_t)dir * (2 * 2048 * DTR);
    const bf16* BT = dtwT2 + (size_t)dir * (1024 * DTR);
    const float* bias = dir ? dtb_b : dtb_f;
    bf16* dltt = dltt2 + (size_t)dir * ((size_t)MROWS * EDIM);
    const int bm = blockIdx.y * 64, bn = blockIdx.x * 64;
    const int bB = bm >> 11, l0 = bm & (LD - 1);
    const int wave = tid >> 6, lane = tid & 63;
    const int wm = (wave >> 1) * 32, wn = (wave & 1) * 32;
    const int lm = lane & 15, lq = lane >> 4;

    {
        int row = tid >> 2, c8 = (tid & 3) * 8;
        const float* p = Ap + (size_t)(bB * 2048 + l0 + row) * DTR + c8;
        float4 v0 = *(const float4*)p, v1 = *(const float4*)(p + 4);
        bf16x8 o;
        o[0]=(__bf16)v0.x; o[1]=(__bf16)v0.y; o[2]=(__bf16)v0.z; o[3]=(__bf16)v0.w;
        o[4]=(__bf16)v1.x; o[5]=(__bf16)v1.y; o[6]=(__bf16)v1.z; o[7]=(__bf16)v1.w;
        *(bf16x8*)&As[row][c8] = o;
    }
    glds16(BT + (size_t)(bn + wave * 16 + (lane >> 2)) * DTR + (lane & 3) * 8,
           &Bs[wave * 16][0]);
    __syncthreads();

    bf16x8 af[2], bfr[2];
#pragma unroll
    for (int i = 0; i < 2; ++i)
        af[i] = *(const bf16x8*)&As[wm + 16 * i + lm][lq * 8];
#pragma unroll
    for (int j = 0; j < 2; ++j)
        bfr[j] = *(const bf16x8*)&Bs[wn + 16 * j + lm][lq * 8];
    f32x4 acc[2][2] = {};
#pragma unroll
    for (int i = 0; i < 2; ++i)
#pragma unroll
        for (int j = 0; j < 2; ++j)
            acc[i][j] = __builtin_amdgcn_mfma_f32_16x16x32_bf16(
                af[i], bfr[j], acc[i][j], 0, 0, 0);

#pragma unroll
    for (int i = 0; i < 2; ++i)
#pragma unroll
        for (int j = 0; j < 2; ++j) {
            int col = wn + 16 * j + lm;
            float bv = bias[bn + col];
#pragma unroll
            for (int r = 0; r < 4; ++r) {
                int row = wm + 16 * i + lq * 4 + r;
                float v = acc[i][j][r] + bv;
                v = (v > 20.f) ? v : log1pf(__expf(v));
                sC[col][row] = v;
            }
        }
    __syncthreads();
    {
        int erow = tid >> 2, l16 = (tid & 3) * 16;
        bf16* d = dltt + ((size_t)bB * EDIM + bn + erow) * LD + l0 + l16;
#pragma unroll
        for (int h = 0; h < 2; ++h) {
            bf16x8 o;
#pragma unroll
            for (int j = 0; j < 8; ++j) o[j] = (__bf16)sC[erow][l16 + h * 8 + j];
            *(bf16x8*)(d + h * 8) = o;
        }
    }
}

// ---------------- scan6 dir-merged: 256 chunks x 8 steps, parallel scan ------
// (round-16 version, verbatim — measured 66.2us / VALUBusy 75% / 40 VGPR)
__global__ __launch_bounds__(256)
void scan6_k(bf16* __restrict__ xct2, const bf16* __restrict__ dltt2,
             const float* __restrict__ dblt2,
             const float* __restrict__ alog_f, const float* __restrict__ alog_b,
             const float* __restrict__ dp_f, const float* __restrict__ dp_b)
{
    __shared__ float sA[NST];
    __shared__ float sWp[NST][4];
    __shared__ float sWs[NST][4];
    const int gid = blockIdx.x;                 // 0..4095
    const int dir = gid >> 11;
    const int bb  = (gid >> 10) & 1;
    const int e   = gid & (EDIM - 1);
    const float* A_log = dir ? alog_b : alog_f;
    const float* Dp    = dir ? dp_b   : dp_f;
    bf16* xct = xct2 + (size_t)dir * ((size_t)MROWS * EDIM);
    const bf16* dltt = dltt2 + (size_t)dir * ((size_t)MROWS * EDIM);
    const float* bt = dblt2 + (size_t)dir * (2 * 64 * LD) + (size_t)bb * 64 * LD;
    const int tid = threadIdx.x;
    const int wave = tid >> 6, lane = tid & 63;
    const size_t baset = ((size_t)bb * EDIM + e) * LD;
    const int l0 = tid * 8;

    if (tid < NST) sA[tid] = -__expf(A_log[e * NST + tid]);

    float xv[8], dv[8], dx[8];
    {
        bf16x8 xr = *(const bf16x8*)(xct + baset + l0);
        bf16x8 dr = *(const bf16x8*)(dltt + baset + l0);
#pragma unroll
        for (int j = 0; j < 8; ++j) { xv[j] = (float)xr[j]; dv[j] = (float)dr[j]; }
    }
#pragma unroll
    for (int j = 0; j < 8; ++j) dx[j] = dv[j] * xv[j];
    __syncthreads();

    float y[8] = {};
    for (int n = 0; n < NST; ++n) {
        const float An = sA[n];
        const float* Bp = bt + (size_t)(DTR + n) * LD + l0;
        const float* Cp = bt + (size_t)(DTR + NST + n) * LD + l0;
        float4 b0 = *(const float4*)Bp, b1 = *(const float4*)(Bp + 4);
        float4 c0 = *(const float4*)Cp, c1 = *(const float4*)(Cp + 4);
        float Br[8] = {b0.x,b0.y,b0.z,b0.w, b1.x,b1.y,b1.z,b1.w};
        float Cr[8] = {c0.x,c0.y,c0.z,c0.w, c1.x,c1.y,c1.z,c1.w};

        // single walk: local state S (h_init=0) and cumprod P, in registers
        float S[8], P[8];
        float h = 0.f, pr = 1.f;
#pragma unroll
        for (int l = 0; l < 8; ++l) {
            float a = __expf(dv[l] * An);
            pr *= a;
            h = fmaf(a, h, dx[l] * Br[l]);
            P[l] = pr; S[l] = h;
        }

        // Kogge-Stone inclusive affine scan across the 64 chunks of this wave
        float p = pr, s = h;
#pragma unroll
        for (int d = 1; d < 64; d <<= 1) {
            float pp = __shfl_up(p, d, 64);
            float sp = __shfl_up(s, d, 64);
            if (lane >= d) { s = fmaf(sp, p, s); p *= pp; }
        }
        // wave totals -> LDS, compose across waves (ascending order)
        if (lane == 63) { sWp[n][wave] = p; sWs[n][wave] = s; }
        __syncthreads();
        float Hoff = 0.f;
#pragma unroll
        for (int w = 0; w < 3; ++w)
            if (w < wave) Hoff = fmaf(sWp[n][w], Hoff, sWs[n][w]);
        // exclusive prefix for this chunk
        float pprev = __shfl_up(p, 1, 64);
        float sprev = __shfl_up(s, 1, 64);
        float H = (lane == 0) ? Hoff : fmaf(pprev, Hoff, sprev);

#pragma unroll
        for (int l = 0; l < 8; ++l)
            y[l] = fmaf(Cr[l], fmaf(P[l], H, S[l]), y[l]);
    }

    const float Dv = Dp[e];
    bf16x8 o;
#pragma unroll
    for (int l = 0; l < 8; ++l) o[l] = (__bf16)fmaf(xv[l], Dv, y[l]);
    *(bf16x8*)(xct + baset + l0) = o;
}

// ---------------- layernorm (bf16 in-place), dir0 rows only ------------------
__global__ __launch_bounds__(256)
void ln_k(bf16* __restrict__ m, const float* __restrict__ gg,
          const float* __restrict__ bb)
{
    int row = (blockIdx.x * 256 + threadIdx.x) >> 6;
    int lane = threadIdx.x & 63;
    bf16* r = m + (size_t)row * DMODEL;
    float v[8], s = 0.f, s2 = 0.f;
#pragma unroll
    for (int i = 0; i < 8; ++i) {
        v[i] = __bfloat162float(r[lane + 64 * i]);
        s += v[i]; s2 = fmaf(v[i], v[i], s2);
    }
#pragma unroll
    for (int off = 32; off >= 1; off >>= 1) {
        s  += __shfl_xor(s, off, 64);
        s2 += __shfl_xor(s2, off, 64);
    }
    float mu = s * (1.f / DMODEL);
    float var = s2 * (1.f / DMODEL) - mu * mu;
    float inv = rsqrtf(var + 1e-5f);
#pragma unroll
    for (int i = 0; i < 8; ++i)
        r[lane + 64 * i] = __float2bfloat16(
            (v[i] - mu) * inv * gg[lane + 64 * i] + bb[lane + 64 * i]);
}

__global__ void sentinel_k(float* __restrict__ o)
{
    int i = blockIdx.x * 256 + threadIdx.x;
    o[i] = 100.0f;
}

extern "C" void kernel_launch(void* const* d_in, const int* in_sizes, int n_in,
                              void* d_out, int out_size, void* d_ws, size_t ws_size,
                              hipStream_t stream)
{
    const float* x    = (const float*)d_in[0];
    const float* n1g  = (const float*)d_in[19];
    const float* n1b  = (const float*)d_in[20];
    const float* fw1  = (const float*)d_in[23];
    const float* fb1  = (const float*)d_in[24];
    const float* fw2  = (const float*)d_in[25];
    const float* fb2  = (const float*)d_in[26];
    float* out = (float*)d_out;

    const size_t MiB = 1024 * 1024;
    const size_t SZ_DM = (size_t)MROWS * DMODEL;
    if (ws_size < 49 * MiB) {
        sentinel_k<<<dim3(SZ_DM / 256), dim3(256), 0, stream>>>(out);
        return;
    }

    // ---- 48.4 MiB layout ----
    char* base = (char*)d_ws;
    bf16* fw1T  = (bf16*)base;                 // [1024][512]        1 MiB
    bf16* fw2T  = (bf16*)(base + 1 * MiB);     // [512][1024]        1 MiB
    bf16* outwT = (bf16*)(base + 2 * MiB);     // [2][512][1024]     2 MiB
    bf16* inwT  = (bf16*)(base + 4 * MiB);     // [2][2048][512]     4 MiB
    bf16* xbf   = (bf16*)(base + 8 * MiB);     // [4096][512]        4 MiB
    char* RA    = base + 12 * MiB;             // 16 MiB: xs2 -> dltt2 -> yrow2 -> ffh2
    bf16* xs2   = (bf16*)RA;                   // [2][4096][1024]
    bf16* dltt2 = (bf16*)RA;
    bf16* yrow2 = (bf16*)RA;
    bf16* ffh2  = (bf16*)RA;
    char* RB    = base + 28 * MiB;             // 16 MiB: xct2 -> mbf2
    bf16* xct2  = (bf16*)RB;                   // [2][2][1024][2048]
    bf16* mbf2  = (bf16*)RB;                   // [2][4096][512]
    float* dblt2 = (float*)(base + 44 * MiB);  // [2][2][64][2048]   2 MiB (rows 32..63 used)
    float* dbldt2 = (float*)(base + 46 * MiB); // [2][2][2048][32]   2 MiB
    bf16* xpT2  = (bf16*)(base + 48 * MiB);               // [2][64][1024]  256 KiB
    bf16* dtwT2 = (bf16*)(base + 48 * MiB + 256 * 1024);  // [2][1024][32]  128 KiB

    const float* inw_f  = (const float*)d_in[1];
    const float* cw_f   = (const float*)d_in[2];
    const float* cb_f   = (const float*)d_in[3];
    const float* xp_f   = (const float*)d_in[4];
    const float* dtw_f  = (const float*)d_in[5];
    const float* dtb_f  = (const float*)d_in[6];
    const float* alog_f = (const float*)d_in[7];
    const float* dp_f   = (const float*)d_in[8];
    const float* outw_f = (const float*)d_in[9];
    const float* inw_b  = (const float*)d_in[10];
    const float* cw_b   = (const float*)d_in[11];
    const float* cb_b   = (const float*)d_in[12];
    const float* xp_b   = (const float*)d_in[13];
    const float* dtw_b  = (const float*)d_in[14];
    const float* dtb_b  = (const float*)d_in[15];
    const float* alog_b = (const float*)d_in[16];
    const float* dp_b   = (const float*)d_in[17];
    const float* outw_b = (const float*)d_in[18];

    dim3 blk(256);
    const size_t U = (size_t)MROWS * EDIM;   // 4,194,304 elems

    // 1. prep: all transposes + xconv
    prep_k<<<dim3(6336), blk, 0, stream>>>(x, xbf, inw_f, inw_b, inwT,
                                           outw_f, outw_b, outwT,
                                           fw1, fw1T, fw2, fw2T,
                                           xp_f, xp_b, xpT2,
                                           dtw_f, dtw_b, dtwT2);
    // 2. G1: xs2[dir] = x(flip d1) @ in_w[:, :1024]   M=4096 N=1024 K=512
    bgemm3_k<128, 0, true, false><<<dim3(8, 32, 2), blk, 0, stream>>>(
        xbf, 0, DMODEL, inwT, (size_t)2048 * 512, DMODEL, nullptr,
        xs2, U, EDIM, nullptr, 0, nullptr, DMODEL);
    // 3. conv + silu + transpose
    conv2_k<<<dim3(16, 64, 2), blk, 0, stream>>>(xs2, cw_f, cb_f, cw_b, cb_b, xct2);
    // 4. G2 (MFMA): dblt rows 32..63 + dbldt row-major
    g2m_k<<<dim3(1, 64, 2), blk, 0, stream>>>(xct2, xpT2, dblt2, dbldt2);
    // 5. G3 (MFMA): dltt2 (over dead xs2)
    g3m_k<<<dim3(16, 64, 2), blk, 0, stream>>>(dbldt2, dtwT2, dtb_f, dtb_b, dltt2);
    // 6. scan (in-place over xct2) — scan6 verbatim
    scan6_k<<<dim3(4096), blk, 0, stream>>>(xct2, dltt2, dblt2,
                                            alog_f, alog_b, dp_f, dp_b);
    // 7. zgate: yrow2 = silu(x @ inw_z) * y  (writes over dead dltt2)
    zgate_k<<<dim3(8, 64, 2), blk, 0, stream>>>(xbf, inwT, xct2, yrow2);
    // 8. G4: mbf2[dir] = y @ out_w   M=4096 N=512 K=1024
    bgemm3_k<64, 0, false, false><<<dim3(8, 32, 2), blk, 0, stream>>>(
        yrow2, U, EDIM, outwT, (size_t)512 * 1024, EDIM, nullptr,
        mbf2, SZ_DM, DMODEL, nullptr, 0, nullptr, EDIM);
    // 9. LN on dir0 half of mbf2 (in place)
    ln_k<<<dim3(MROWS / 4), blk, 0, stream>>>(mbf2, n1g, n1b);
    // 10. G5: ffh2[dir] = relu(m @ fw1 + fb1)   M=4096 N=1024 K=512
    bgemm3_k<128, 2, false, false><<<dim3(8, 32, 2), blk, 0, stream>>>(
        mbf2, SZ_DM, DMODEL, fw1T, 0, DMODEL, fb1,
        ffh2, U, DFF, nullptr, 0, nullptr, DMODEL);
    // 11. G6 fused (concat-K): out = ffh_f@fw2 + ffh_b@fw2 + 2*fb2 + m_f + m_b
    bgemm3_k<64, 5, false, true><<<dim3(8, 32, 1), blk, 0, stream>>>(
        ffh2, U, DFF, fw2T, 0, DFF, fb2,
        nullptr, 0, DMODEL, mbf2, SZ_DM, out, 2 * DFF);
}

// Round 8
// 369.627 us; speedup vs baseline: 1.0020x; 1.0004x over previous
//
#include <hip/hip_runtime.h>
#include <hip/hip_bf16.h>
#include <math.h>

// BiMambaEncoderLayer: B=2, L=2048, D_MODEL=512, ED=1024, N=16, DCONV=4,
// DT_RANK=32, D_FF=1024. f32 in/out.
// Round-23: GEMM grid-occupancy fix. K-loop schedule experiments (BK=64,
// 2-phase dbuf) were both neutral -> the GEMMs are not schedule-bound but
// GRID-bound: 128x128 tiles gave 512 blocks = 2/CU (G6: 1/CU) on 256 CUs,
// so barriers idle whole CUs. Tiles shrunk to reach >=4 blocks/CU:
//   G1/G5: 128x64 -> (16,32,2)=1024 blocks;  G4: 64x64 -> 1024;
//   G6: 64x64 -> 512 (N=512 limit; longest K amortizes).
// bgemm3 now templated on BM,BN. scan6 verbatim (65us known-good).
// 11 dispatches, 48.4 MiB workspace.

#define BD 2
#define LD 2048
#define DMODEL 512
#define EDIM 1024
#define NST 16
#define DTR 32
#define DFF 1024
#define MROWS (BD*LD)   // 4096

typedef __hip_bfloat16 bf16;
typedef __bf16 bf16x8 __attribute__((ext_vector_type(8)));
typedef __bf16 bf16x4 __attribute__((ext_vector_type(4)));
typedef float  f32x4  __attribute__((ext_vector_type(4)));

__device__ __forceinline__ float sig_(float x) { return 1.f / (1.f + __expf(-x)); }

// async 16B global->LDS (wave-uniform LDS base, per-lane global addr)
__device__ __forceinline__ void glds16(const void* g, void* l)
{
    __builtin_amdgcn_global_load_lds(
        (const __attribute__((address_space(1))) void*)g,
        (__attribute__((address_space(3))) void*)l, 16, 0, 0);
}

// ---------------- prep: all weight transposes + x->bf16, one dispatch --------
// [0,2048) xconv | [2048,4096) inwT | [4096,5120) outwT | [5120,5632) fw1T |
// [5632,6144) fw2T | [6144,6272) xpT | [6272,6336) dtwT
__global__ __launch_bounds__(256)
void prep_k(const float* __restrict__ x, bf16* __restrict__ xbf,
            const float* __restrict__ inw_f, const float* __restrict__ inw_b,
            bf16* __restrict__ inwT,
            const float* __restrict__ outw_f, const float* __restrict__ outw_b,
            bf16* __restrict__ outwT,
            const float* __restrict__ fw1, bf16* __restrict__ fw1T,
            const float* __restrict__ fw2, bf16* __restrict__ fw2T,
            const float* __restrict__ xp_f, const float* __restrict__ xp_b,
            bf16* __restrict__ xpT,
            const float* __restrict__ dtw_f, const float* __restrict__ dtw_b,
            bf16* __restrict__ dtwT)
{
    const int bid = blockIdx.x, tid = threadIdx.x;
    if (bid < 2048) {
        size_t i = (size_t)bid * 1024 + tid * 4;
        float4 v = *(const float4*)(x + i);
        bf16* o = xbf + i;
        o[0] = __float2bfloat16(v.x); o[1] = __float2bfloat16(v.y);
        o[2] = __float2bfloat16(v.z); o[3] = __float2bfloat16(v.w);
        return;
    }
    const float* W; bf16* WT; int R, C, cx, ry;
    if (bid < 4096) {
        int d = (bid - 2048) >> 10, t = (bid - 2048) & 1023;
        W = d ? inw_b : inw_f; WT = inwT + (size_t)d * 2048 * 512;
        R = 512; C = 2048; cx = t & 63; ry = t >> 6;
    } else if (bid < 5120) {
        int d = (bid - 4096) >> 9, t = (bid - 4096) & 511;
        W = d ? outw_b : outw_f; WT = outwT + (size_t)d * 512 * 1024;
        R = 1024; C = 512; cx = t & 15; ry = t >> 4;
    } else if (bid < 5632) {
        int t = bid - 5120; W = fw1; WT = fw1T; R = 512; C = 1024;
        cx = t & 31; ry = t >> 5;
    } else if (bid < 6144) {
        int t = bid - 5632; W = fw2; WT = fw2T; R = 1024; C = 512;
        cx = t & 15; ry = t >> 4;
    } else if (bid < 6272) {
        int d = (bid - 6144) >> 6, t = (bid - 6144) & 63;
        W = d ? xp_b : xp_f; WT = xpT + (size_t)d * 64 * 1024;
        R = 1024; C = 64; cx = t & 1; ry = t >> 1;
    } else {
        int d = (bid - 6272) >> 5, t = (bid - 6272) & 31;
        W = d ? dtw_b : dtw_f; WT = dtwT + (size_t)d * 1024 * DTR;
        R = 32; C = 1024; cx = t; ry = 0;
    }
    __shared__ float tt[32][33];
    const int c0 = cx * 32, r0 = ry * 32;
    const int col = tid & 31, rr = tid >> 5;
#pragma unroll
    for (int p = 0; p < 4; ++p)
        tt[p * 8 + rr][col] = W[(size_t)(r0 + p * 8 + rr) * C + c0 + col];
    __syncthreads();
#pragma unroll
    for (int p = 0; p < 4; ++p)
        WT[(size_t)(c0 + p * 8 + rr) * R + r0 + col] =
            __float2bfloat16(tt[col][p * 8 + rr]);
}

// ---------------- bgemm3: BMxBN MFMA GEMM, BK=32, 2-phase dbuf --------------
// BM in {64,128}, BN in {64,128}. STAGE(t+1) before COMPUTE(t); one barrier
// per K-step. Wave quadrants: wm=(wave>>1)*(BM/2), wn=(wave&1)*(BN/2).
template<int BM, int BN, int MODE, bool FLIPD1, bool CATK>
__global__ __launch_bounds__(256)
void bgemm3_k(const bf16* __restrict__ A, size_t Astr, int lda,
              const bf16* __restrict__ BT, size_t Bstr, int ldb,
              const float* __restrict__ bias,
              bf16* __restrict__ Cb, size_t Cstr, int ldc,
              const bf16* __restrict__ mp, size_t mpStr,
              float* __restrict__ outp, int K)
{
    constexpr int BK = 32;
    constexpr int FRm = BM / 32, FRn = BN / 32;
    constexpr int KH = DFF;   // concat-K half length (1024)
    __shared__ __align__(16) bf16 As[2][BM][BK];
    __shared__ __align__(16) bf16 Bs[2][BN][BK];
    const int tid = threadIdx.x;
    const int dir = blockIdx.z;
    const bool flip = FLIPD1 && (dir == 1);
    const bf16* Ad = A + (CATK ? (size_t)0 : (size_t)dir * Astr);
    const bf16* Bd = BT + (size_t)dir * Bstr;
    const int bm = blockIdx.y * BM, bn = blockIdx.x * BN;
    const int wave = tid >> 6, lane = tid & 63;
    const int wm = (wave >> 1) * (BM / 2), wn = (wave & 1) * (BN / 2);
    const int lm = lane & 15, lq = lane >> 4;
    const int lrow = lane >> 2, lcol = (lane & 3) * 8;  // 16 rows x 64B / wave
    f32x4 acc[FRm][FRn] = {};

    auto STAGE = [&](int buf, int k0) {
        const bf16* Ab = Ad;
        int ka = k0;
        if (CATK && k0 >= KH) { Ab = A + Astr; ka = k0 - KH; }
        const int kb = CATK ? (k0 & (KH - 1)) : k0;
#pragma unroll
        for (int c = 0; c < BM / 64; ++c) {
            int row = c * 64 + wave * 16 + lrow;
            int gm = bm + row;
            if (flip) gm = (gm & ~(LD - 1)) + (LD - 1 - (gm & (LD - 1)));
            glds16(Ab + (size_t)gm * lda + ka + lcol,
                   &As[buf][c * 64 + wave * 16][0]);
        }
#pragma unroll
        for (int c = 0; c < BN / 64; ++c) {
            int row = c * 64 + wave * 16 + lrow;
            glds16(Bd + (size_t)(bn + row) * ldb + kb + lcol,
                   &Bs[buf][c * 64 + wave * 16][0]);
        }
    };
    auto COMPUTE = [&](int buf) {
        bf16x8 af[FRm], bfr[FRn];
#pragma unroll
        for (int i = 0; i < FRm; ++i)
            af[i] = *(const bf16x8*)&As[buf][wm + 16 * i + lm][lq * 8];
#pragma unroll
        for (int j = 0; j < FRn; ++j)
            bfr[j] = *(const bf16x8*)&Bs[buf][wn + 16 * j + lm][lq * 8];
#pragma unroll
        for (int i = 0; i < FRm; ++i)
#pragma unroll
            for (int j = 0; j < FRn; ++j)
                acc[i][j] = __builtin_amdgcn_mfma_f32_16x16x32_bf16(
                    af[i], bfr[j], acc[i][j], 0, 0, 0);
    };

    STAGE(0, 0);
    __syncthreads();
    int cur = 0;
    for (int k0 = BK; k0 < K; k0 += BK) {
        STAGE(cur ^ 1, k0);   // prefetch next tile (flies under the MFMA)
        COMPUTE(cur);
        __syncthreads();      // drains prefetch vmcnt + our lgkm reads
        cur ^= 1;
    }
    COMPUTE(cur);

    bf16* Cd = (MODE == 5) ? nullptr : Cb + (size_t)dir * Cstr;
#pragma unroll
    for (int i = 0; i < FRm; ++i) {
#pragma unroll
        for (int j = 0; j < FRn; ++j) {
            int col = bn + wn + 16 * j + lm;
            float bv = (MODE == 2) ? bias[col]
                     : (MODE == 5) ? 2.f * bias[col] : 0.f;
#pragma unroll
            for (int r = 0; r < 4; ++r) {
                int row = bm + wm + 16 * i + lq * 4 + r;
                float v = acc[i][j][r] + bv;
                size_t idx = (size_t)row * ldc + col;
                if (MODE == 0)      Cd[idx] = __float2bfloat16(v);
                else if (MODE == 2) Cd[idx] = __float2bfloat16(fmaxf(v, 0.f));
                else {
                    float m2 = __bfloat162float(mp[idx])
                             + __bfloat162float(mp[mpStr + idx]);
                    outp[idx] = v + m2;
                }
            }
        }
    }
}

// ---------------- zgate: yrow = silu(x(flip?) @ inw_z) * y2t^T ---------------
__global__ __launch_bounds__(256)
void zgate_k(const bf16* __restrict__ xbf, const bf16* __restrict__ inwT,
             const bf16* __restrict__ y2t_all, bf16* __restrict__ yrow_all)
{
    __shared__ __align__(16) bf16 As[64][40];
    __shared__ __align__(16) bf16 Bs[128][40];
    __shared__ __bf16 sy[64][130];
    const int tid = threadIdx.x;
    const int dir = blockIdx.z;
    const bf16* Bd = inwT + (size_t)dir * (2048 * 512) + (size_t)1024 * 512;
    const bf16* y2t = y2t_all + (size_t)dir * ((size_t)MROWS * EDIM);
    bf16* yrow = yrow_all + (size_t)dir * ((size_t)MROWS * EDIM);
    const int bm = blockIdx.y * 64, bn = blockIdx.x * 128;
    const int wave = tid >> 6, lane = tid & 63;
    const int wm = (wave >> 1) * 32, wn = (wave & 1) * 64;
    const int lm = lane & 15, lq = lane >> 4;
    f32x4 acc[2][4] = {};

    for (int k0 = 0; k0 < 512; k0 += 32) {
        {
            int row = tid >> 2, col = (tid & 3) * 8;
            int gm = bm + row;
            if (dir == 1) gm = (gm & ~(LD - 1)) + (LD - 1 - (gm & (LD - 1)));
            *(bf16x8*)&As[row][col] =
                *(const bf16x8*)(xbf + (size_t)gm * 512 + k0 + col);
        }
#pragma unroll
        for (int p = 0; p < 2; ++p) {
            int row = p * 64 + (tid >> 2), col = (tid & 3) * 8;
            *(bf16x8*)&Bs[row][col] =
                *(const bf16x8*)(Bd + (size_t)(bn + row) * 512 + k0 + col);
        }
        __syncthreads();
        bf16x8 af[2], bfr[4];
#pragma unroll
        for (int i = 0; i < 2; ++i)
            af[i] = *(const bf16x8*)&As[wm + 16 * i + lm][lq * 8];
#pragma unroll
        for (int j = 0; j < 4; ++j)
            bfr[j] = *(const bf16x8*)&Bs[wn + 16 * j + lm][lq * 8];
#pragma unroll
        for (int i = 0; i < 2; ++i)
#pragma unroll
            for (int j = 0; j < 4; ++j)
                acc[i][j] = __builtin_amdgcn_mfma_f32_16x16x32_bf16(
                    af[i], bfr[j], acc[i][j], 0, 0, 0);
        __syncthreads();
    }

    {
        const int b = bm >> 11, l0 = bm & (LD - 1);
        int e = tid >> 1, lh = (tid & 1) * 32;
        const bf16* yp = y2t + ((size_t)b * EDIM + bn + e) * LD + l0 + lh;
#pragma unroll
        for (int i = 0; i < 4; ++i) {
            bf16x8 v = *(const bf16x8*)(yp + i * 8);
#pragma unroll
            for (int j = 0; j < 8; ++j) sy[lh + i * 8 + j][e] = v[j];
        }
    }
    __syncthreads();
#pragma unroll
    for (int i = 0; i < 2; ++i) {
#pragma unroll
        for (int j = 0; j < 4; ++j) {
            int col = bn + wn + 16 * j + lm;
#pragma unroll
            for (int r = 0; r < 4; ++r) {
                int row = bm + wm + 16 * i + lq * 4 + r;
                float z = acc[i][j][r];
                float g = z * sig_(z);
                float y = (float)sy[(row - bm)][col - bn];
                yrow[(size_t)row * EDIM + col] = __float2bfloat16(g * y);
            }
        }
    }
}

// ---------------- conv(4)+bias+silu+transpose, dir-merged, vectorized --------
__global__ __launch_bounds__(256)
void conv2_k(const bf16* __restrict__ xs2,
             const float* __restrict__ cw_f, const float* __restrict__ cb_f,
             const float* __restrict__ cw_b, const float* __restrict__ cb_b,
             bf16* __restrict__ xct2)
{
    __shared__ float sxs[67][65];
    __shared__ float sout[64][65];
    const int tid = threadIdx.x;
    const int dir = blockIdx.z;
    const bf16* xs = xs2 + (size_t)dir * ((size_t)MROWS * EDIM);
    const float* w  = dir ? cw_b : cw_f;
    const float* cb = dir ? cb_b : cb_f;
    bf16* xct = xct2 + (size_t)dir * ((size_t)MROWS * EDIM);
    const int e0 = blockIdx.x * 64;
    const int bl0 = blockIdx.y * 64;
    const int lloc0 = bl0 & (LD - 1);
    const int b = bl0 >> 11;
    {
        int c8 = (tid & 7) * 8;
#pragma unroll
        for (int i = 0; i < 3; ++i) {
            int hr = i * 32 + (tid >> 3);
            if (hr < 67) {
                int lr = lloc0 + hr - 3;
                if (lr >= 0) {
                    bf16x8 v = *(const bf16x8*)(xs +
                        (size_t)(bl0 + hr - 3) * EDIM + e0 + c8);
#pragma unroll
                    for (int j = 0; j < 8; ++j) sxs[hr][c8 + j] = (float)v[j];
                } else {
#pragma unroll
                    for (int j = 0; j < 8; ++j) sxs[hr][c8 + j] = 0.f;
                }
            }
        }
    }
    __syncthreads();
    {
        int lr4 = tid >> 6, e = tid & 63;
        float w0 = w[(e0 + e) * 4 + 0], w1 = w[(e0 + e) * 4 + 1];
        float w2 = w[(e0 + e) * 4 + 2], w3 = w[(e0 + e) * 4 + 3];
        float cbv = cb[e0 + e];
#pragma unroll
        for (int i = 0; i < 16; ++i) {
            int lr = i * 4 + lr4;
            float acc = cbv;
            acc = fmaf(sxs[lr + 0][e], w0, acc);
            acc = fmaf(sxs[lr + 1][e], w1, acc);
            acc = fmaf(sxs[lr + 2][e], w2, acc);
            acc = fmaf(sxs[lr + 3][e], w3, acc);
            sout[e][lr] = acc * sig_(acc);
        }
    }
    __syncthreads();
    {
        int l8 = (tid & 7) * 8;
#pragma unroll
        for (int i = 0; i < 2; ++i) {
            int er = i * 32 + (tid >> 3);
            bf16x8 o;
#pragma unroll
            for (int j = 0; j < 8; ++j) o[j] = (__bf16)sout[er][l8 + j];
            *(bf16x8*)(xct + ((size_t)b * EDIM + e0 + er) * LD + lloc0 + l8) = o;
        }
    }
}

// ---------------- g2m: MFMA dbl = xc @ xproj (dt rows row-major) -------------
__global__ __launch_bounds__(256)
void g2m_k(const bf16* __restrict__ xct2, const bf16* __restrict__ xpT2,
           float* __restrict__ dblt2, float* __restrict__ dbldt2)
{
    __shared__ float As[64][33];            // [l][e] transposed, <=2-way banks
    __shared__ __align__(16) bf16 Bs[64][32];
    __shared__ float sC[32][65];            // n-rows 32..63 staging
    const int tid = threadIdx.x;
    const int dir = blockIdx.z;
    const bf16* xct = xct2 + (size_t)dir * ((size_t)MROWS * EDIM);
    const bf16* xpT = xpT2 + (size_t)dir * (64 * 1024);
    float* dblt = dblt2 + (size_t)dir * (2 * 64 * LD);
    float* dbldt = dbldt2 + (size_t)dir * (2 * 2048 * DTR);
    const int bm = blockIdx.y * 64;
    const int bB = bm >> 11, l0 = bm & (LD - 1);
    const int wave = tid >> 6, lane = tid & 63;
    const int wm = (wave >> 1) * 32, wn = (wave & 1) * 32;
    const int lm = lane & 15, lq = lane >> 4;
    const int er = tid >> 3, l8 = (tid & 7) * 8;   // A-stage coords
    f32x4 acc[2][2] = {};

    for (int k0 = 0; k0 < EDIM; k0 += 32) {
        glds16(xpT + (size_t)(wave * 16 + (lane >> 2)) * 1024 + k0 + (lane & 3) * 8,
               &Bs[wave * 16][0]);
        {
            bf16x8 v = *(const bf16x8*)(xct +
                ((size_t)bB * EDIM + k0 + er) * LD + l0 + l8);
#pragma unroll
            for (int j = 0; j < 8; ++j) As[l8 + j][er] = (float)v[j];
        }
        __syncthreads();
        bf16x8 af[2], bfr[2];
#pragma unroll
        for (int i = 0; i < 2; ++i) {
            int row = wm + 16 * i + lm;
#pragma unroll
            for (int j = 0; j < 8; ++j) af[i][j] = (__bf16)As[row][lq * 8 + j];
        }
#pragma unroll
        for (int j = 0; j < 2; ++j)
            bfr[j] = *(const bf16x8*)&Bs[wn + 16 * j + lm][lq * 8];
#pragma unroll
        for (int i = 0; i < 2; ++i)
#pragma unroll
            for (int j = 0; j < 2; ++j)
                acc[i][j] = __builtin_amdgcn_mfma_f32_16x16x32_bf16(
                    af[i], bfr[j], acc[i][j], 0, 0, 0);
        __syncthreads();
    }
    if (wn == 0) {
#pragma unroll
        for (int i = 0; i < 2; ++i)
#pragma unroll
            for (int j = 0; j < 2; ++j) {
                int col = 16 * j + lm;
#pragma unroll
                for (int r = 0; r < 4; ++r) {
                    int row = wm + 16 * i + lq * 4 + r;
                    dbldt[(size_t)(bB * 2048 + l0 + row) * DTR + col] =
                        acc[i][j][r];
                }
            }
    } else {
#pragma unroll
        for (int i = 0; i < 2; ++i)
#pragma unroll
            for (int j = 0; j < 2; ++j) {
                int col = 16 * j + lm;
#pragma unroll
                for (int r = 0; r < 4; ++r)
                    sC[col][wm + 16 * i + lq * 4 + r] = acc[i][j][r];
            }
    }
    __syncthreads();
    {
        int nr = tid >> 3, ll = (tid & 7) * 8;
        float4 v0 = *(const float4*)&sC[nr][ll];
        float4 v1 = *(const float4*)&sC[nr][ll + 4];
        float* d = dblt + (size_t)(bB * 64 + 32 + nr) * LD + l0 + ll;
        *(float4*)d = v0; *(float4*)(d + 4) = v1;
    }
}

// ---------------- g3m: MFMA dlt_t = softplus(dbldt @ dtw + b)^T --------------
__global__ __launch_bounds__(256)
void g3m_k(const float* __restrict__ dbldt2, const bf16* __restrict__ dtwT2,
           const float* __restrict__ dtb_f, const float* __restrict__ dtb_b,
           bf16* __restrict__ dltt2)
{
    __shared__ __align__(16) bf16 As[64][40];
    __shared__ __align__(16) bf16 Bs[64][32];
    __shared__ float sC[64][65];
    const int tid = threadIdx.x;
    const int dir = blockIdx.z;
    const float* Ap = dbldt2 + (size_t)dir * (2 * 2048 * DTR);
    const bf16* BT = dtwT2 + (size_t)dir * (1024 * DTR);
    const float* bias = dir ? dtb_b : dtb_f;
    bf16* dltt = dltt2 + (size_t)dir * ((size_t)MROWS * EDIM);
    const int bm = blockIdx.y * 64, bn = blockIdx.x * 64;
    const int bB = bm >> 11, l0 = bm & (LD - 1);
    const int wave = tid >> 6, lane = tid & 63;
    const int wm = (wave >> 1) * 32, wn = (wave & 1) * 32;
    const int lm = lane & 15, lq = lane >> 4;

    {
        int row = tid >> 2, c8 = (tid & 3) * 8;
        const float* p = Ap + (size_t)(bB * 2048 + l0 + row) * DTR + c8;
        float4 v0 = *(const float4*)p, v1 = *(const float4*)(p + 4);
        bf16x8 o;
        o[0]=(__bf16)v0.x; o[1]=(__bf16)v0.y; o[2]=(__bf16)v0.z; o[3]=(__bf16)v0.w;
        o[4]=(__bf16)v1.x; o[5]=(__bf16)v1.y; o[6]=(__bf16)v1.z; o[7]=(__bf16)v1.w;
        *(bf16x8*)&As[row][c8] = o;
    }
    glds16(BT + (size_t)(bn + wave * 16 + (lane >> 2)) * DTR + (lane & 3) * 8,
           &Bs[wave * 16][0]);
    __syncthreads();

    bf16x8 af[2], bfr[2];
#pragma unroll
    for (int i = 0; i < 2; ++i)
        af[i] = *(const bf16x8*)&As[wm + 16 * i + lm][lq * 8];
#pragma unroll
    for (int j = 0; j < 2; ++j)
        bfr[j] = *(const bf16x8*)&Bs[wn + 16 * j + lm][lq * 8];
    f32x4 acc[2][2] = {};
#pragma unroll
    for (int i = 0; i < 2; ++i)
#pragma unroll
        for (int j = 0; j < 2; ++j)
            acc[i][j] = __builtin_amdgcn_mfma_f32_16x16x32_bf16(
                af[i], bfr[j], acc[i][j], 0, 0, 0);

#pragma unroll
    for (int i = 0; i < 2; ++i)
#pragma unroll
        for (int j = 0; j < 2; ++j) {
            int col = wn + 16 * j + lm;
            float bv = bias[bn + col];
#pragma unroll
            for (int r = 0; r < 4; ++r) {
                int row = wm + 16 * i + lq * 4 + r;
                float v = acc[i][j][r] + bv;
                v = (v > 20.f) ? v : log1pf(__expf(v));
                sC[col][row] = v;
            }
        }
    __syncthreads();
    {
        int erow = tid >> 2, l16 = (tid & 3) * 16;
        bf16* d = dltt + ((size_t)bB * EDIM + bn + erow) * LD + l0 + l16;
#pragma unroll
        for (int h = 0; h < 2; ++h) {
            bf16x8 o;
#pragma unroll
            for (int j = 0; j < 8; ++j) o[j] = (__bf16)sC[erow][l16 + h * 8 + j];
            *(bf16x8*)(d + h * 8) = o;
        }
    }
}

// ---------------- scan6 dir-merged: 256 chunks x 8 steps, parallel scan ------
// (round-16 version, verbatim — measured ~65us / VALUBusy 74% / 40 VGPR)
__global__ __launch_bounds__(256)
void scan6_k(bf16* __restrict__ xct2, const bf16* __restrict__ dltt2,
             const float* __restrict__ dblt2,
             const float* __restrict__ alog_f, const float* __restrict__ alog_b,
             const float* __restrict__ dp_f, const float* __restrict__ dp_b)
{
    __shared__ float sA[NST];
    __shared__ float sWp[NST][4];
    __shared__ float sWs[NST][4];
    const int gid = blockIdx.x;                 // 0..4095
    const int dir = gid >> 11;
    const int bb  = (gid >> 10) & 1;
    const int e   = gid & (EDIM - 1);
    const float* A_log = dir ? alog_b : alog_f;
    const float* Dp    = dir ? dp_b   : dp_f;
    bf16* xct = xct2 + (size_t)dir * ((size_t)MROWS * EDIM);
    const bf16* dltt = dltt2 + (size_t)dir * ((size_t)MROWS * EDIM);
    const float* bt = dblt2 + (size_t)dir * (2 * 64 * LD) + (size_t)bb * 64 * LD;
    const int tid = threadIdx.x;
    const int wave = tid >> 6, lane = tid & 63;
    const size_t baset = ((size_t)bb * EDIM + e) * LD;
    const int l0 = tid * 8;

    if (tid < NST) sA[tid] = -__expf(A_log[e * NST + tid]);

    float xv[8], dv[8], dx[8];
    {
        bf16x8 xr = *(const bf16x8*)(xct + baset + l0);
        bf16x8 dr = *(const bf16x8*)(dltt + baset + l0);
#pragma unroll
        for (int j = 0; j < 8; ++j) { xv[j] = (float)xr[j]; dv[j] = (float)dr[j]; }
    }
#pragma unroll
    for (int j = 0; j < 8; ++j) dx[j] = dv[j] * xv[j];
    __syncthreads();

    float y[8] = {};
    for (int n = 0; n < NST; ++n) {
        const float An = sA[n];
        const float* Bp = bt + (size_t)(DTR + n) * LD + l0;
        const float* Cp = bt + (size_t)(DTR + NST + n) * LD + l0;
        float4 b0 = *(const float4*)Bp, b1 = *(const float4*)(Bp + 4);
        float4 c0 = *(const float4*)Cp, c1 = *(const float4*)(Cp + 4);
        float Br[8] = {b0.x,b0.y,b0.z,b0.w, b1.x,b1.y,b1.z,b1.w};
        float Cr[8] = {c0.x,c0.y,c0.z,c0.w, c1.x,c1.y,c1.z,c1.w};

        // single walk: local state S (h_init=0) and cumprod P, in registers
        float S[8], P[8];
        float h = 0.f, pr = 1.f;
#pragma unroll
        for (int l = 0; l < 8; ++l) {
            float a = __expf(dv[l] * An);
            pr *= a;
            h = fmaf(a, h, dx[l] * Br[l]);
            P[l] = pr; S[l] = h;
        }

        // Kogge-Stone inclusive affine scan across the 64 chunks of this wave
        float p = pr, s = h;
#pragma unroll
        for (int d = 1; d < 64; d <<= 1) {
            float pp = __shfl_up(p, d, 64);
            float sp = __shfl_up(s, d, 64);
            if (lane >= d) { s = fmaf(sp, p, s); p *= pp; }
        }
        // wave totals -> LDS, compose across waves (ascending order)
        if (lane == 63) { sWp[n][wave] = p; sWs[n][wave] = s; }
        __syncthreads();
        float Hoff = 0.f;
#pragma unroll
        for (int w = 0; w < 3; ++w)
            if (w < wave) Hoff = fmaf(sWp[n][w], Hoff, sWs[n][w]);
        // exclusive prefix for this chunk
        float pprev = __shfl_up(p, 1, 64);
        float sprev = __shfl_up(s, 1, 64);
        float H = (lane == 0) ? Hoff : fmaf(pprev, Hoff, sprev);

#pragma unroll
        for (int l = 0; l < 8; ++l)
            y[l] = fmaf(Cr[l], fmaf(P[l], H, S[l]), y[l]);
    }

    const float Dv = Dp[e];
    bf16x8 o;
#pragma unroll
    for (int l = 0; l < 8; ++l) o[l] = (__bf16)fmaf(xv[l], Dv, y[l]);
    *(bf16x8*)(xct + baset + l0) = o;
}

// ---------------- layernorm (bf16 in-place), dir0 rows only ------------------
__global__ __launch_bounds__(256)
void ln_k(bf16* __restrict__ m, const float* __restrict__ gg,
          const float* __restrict__ bb)
{
    int row = (blockIdx.x * 256 + threadIdx.x) >> 6;
    int lane = threadIdx.x & 63;
    bf16* r = m + (size_t)row * DMODEL;
    float v[8], s = 0.f, s2 = 0.f;
#pragma unroll
    for (int i = 0; i < 8; ++i) {
        v[i] = __bfloat162float(r[lane + 64 * i]);
        s += v[i]; s2 = fmaf(v[i], v[i], s2);
    }
#pragma unroll
    for (int off = 32; off >= 1; off >>= 1) {
        s  += __shfl_xor(s, off, 64);
        s2 += __shfl_xor(s2, off, 64);
    }
    float mu = s * (1.f / DMODEL);
    float var = s2 * (1.f / DMODEL) - mu * mu;
    float inv = rsqrtf(var + 1e-5f);
#pragma unroll
    for (int i = 0; i < 8; ++i)
        r[lane + 64 * i] = __float2bfloat16(
            (v[i] - mu) * inv * gg[lane + 64 * i] + bb[lane + 64 * i]);
}

__global__ void sentinel_k(float* __restrict__ o)
{
    int i = blockIdx.x * 256 + threadIdx.x;
    o[i] = 100.0f;
}

extern "C" void kernel_launch(void* const* d_in, const int* in_sizes, int n_in,
                              void* d_out, int out_size, void* d_ws, size_t ws_size,
                              hipStream_t stream)
{
    const float* x    = (const float*)d_in[0];
    const float* n1g  = (const float*)d_in[19];
    const float* n1b  = (const float*)d_in[20];
    const float* fw1  = (const float*)d_in[23];
    const float* fb1  = (const float*)d_in[24];
    const float* fw2  = (const float*)d_in[25];
    const float* fb2  = (const float*)d_in[26];
    float* out = (float*)d_out;

    const size_t MiB = 1024 * 1024;
    const size_t SZ_DM = (size_t)MROWS * DMODEL;
    if (ws_size < 49 * MiB) {
        sentinel_k<<<dim3(SZ_DM / 256), dim3(256), 0, stream>>>(out);
        return;
    }

    // ---- 48.4 MiB layout ----
    char* base = (char*)d_ws;
    bf16* fw1T  = (bf16*)base;                 // [1024][512]        1 MiB
    bf16* fw2T  = (bf16*)(base + 1 * MiB);     // [512][1024]        1 MiB
    bf16* outwT = (bf16*)(base + 2 * MiB);     // [2][512][1024]     2 MiB
    bf16* inwT  = (bf16*)(base + 4 * MiB);     // [2][2048][512]     4 MiB
    bf16* xbf   = (bf16*)(base + 8 * MiB);     // [4096][512]        4 MiB
    char* RA    = base + 12 * MiB;             // 16 MiB: xs2 -> dltt2 -> yrow2 -> ffh2
    bf16* xs2   = (bf16*)RA;                   // [2][4096][1024]
    bf16* dltt2 = (bf16*)RA;
    bf16* yrow2 = (bf16*)RA;
    bf16* ffh2  = (bf16*)RA;
    char* RB    = base + 28 * MiB;             // 16 MiB: xct2 -> mbf2
    bf16* xct2  = (bf16*)RB;                   // [2][2][1024][2048]
    bf16* mbf2  = (bf16*)RB;                   // [2][4096][512]
    float* dblt2 = (float*)(base + 44 * MiB);  // [2][2][64][2048]   2 MiB (rows 32..63 used)
    float* dbldt2 = (float*)(base + 46 * MiB); // [2][2][2048][32]   2 MiB
    bf16* xpT2  = (bf16*)(base + 48 * MiB);               // [2][64][1024]  256 KiB
    bf16* dtwT2 = (bf16*)(base + 48 * MiB + 256 * 1024);  // [2][1024][32]  128 KiB

    const float* inw_f  = (const float*)d_in[1];
    const float* cw_f   = (const float*)d_in[2];
    const float* cb_f   = (const float*)d_in[3];
    const float* xp_f   = (const float*)d_in[4];
    const float* dtw_f  = (const float*)d_in[5];
    const float* dtb_f  = (const float*)d_in[6];
    const float* alog_f = (const float*)d_in[7];
    const float* dp_f   = (const float*)d_in[8];
    const float* outw_f = (const float*)d_in[9];
    const float* inw_b  = (const float*)d_in[10];
    const float* cw_b   = (const float*)d_in[11];
    const float* cb_b   = (const float*)d_in[12];
    const float* xp_b   = (const float*)d_in[13];
    const float* dtw_b  = (const float*)d_in[14];
    const float* dtb_b  = (const float*)d_in[15];
    const float* alog_b = (const float*)d_in[16];
    const float* dp_b   = (const float*)d_in[17];
    const float* outw_b = (const float*)d_in[18];

    dim3 blk(256);
    const size_t U = (size_t)MROWS * EDIM;   // 4,194,304 elems

    // 1. prep: all transposes + xconv
    prep_k<<<dim3(6336), blk, 0, stream>>>(x, xbf, inw_f, inw_b, inwT,
                                           outw_f, outw_b, outwT,
                                           fw1, fw1T, fw2, fw2T,
                                           xp_f, xp_b, xpT2,
                                           dtw_f, dtw_b, dtwT2);
    // 2. G1: xs2[dir] = x(flip d1) @ in_w[:, :1024]   M=4096 N=1024 K=512
    //    128x64 tile -> (16,32,2) = 1024 blocks = 4/CU
    bgemm3_k<128, 64, 0, true, false><<<dim3(16, 32, 2), blk, 0, stream>>>(
        xbf, 0, DMODEL, inwT, (size_t)2048 * 512, DMODEL, nullptr,
        xs2, U, EDIM, nullptr, 0, nullptr, DMODEL);
    // 3. conv + silu + transpose
    conv2_k<<<dim3(16, 64, 2), blk, 0, stream>>>(xs2, cw_f, cb_f, cw_b, cb_b, xct2);
    // 4. G2 (MFMA): dblt rows 32..63 + dbldt row-major
    g2m_k<<<dim3(1, 64, 2), blk, 0, stream>>>(xct2, xpT2, dblt2, dbldt2);
    // 5. G3 (MFMA): dltt2 (over dead xs2)
    g3m_k<<<dim3(16, 64, 2), blk, 0, stream>>>(dbldt2, dtwT2, dtb_f, dtb_b, dltt2);
    // 6. scan (in-place over xct2) — scan6 verbatim
    scan6_k<<<dim3(4096), blk, 0, stream>>>(xct2, dltt2, dblt2,
                                            alog_f, alog_b, dp_f, dp_b);
    // 7. zgate: yrow2 = silu(x @ inw_z) * y  (writes over dead dltt2)
    zgate_k<<<dim3(8, 64, 2), blk, 0, stream>>>(xbf, inwT, xct2, yrow2);
    // 8. G4: mbf2[dir] = y @ out_w   M=4096 N=512 K=1024
    //    64x64 tile -> (8,64,2) = 1024 blocks = 4/CU
    bgemm3_k<64, 64, 0, false, false><<<dim3(8, 64, 2), blk, 0, stream>>>(
        yrow2, U, EDIM, outwT, (size_t)512 * 1024, EDIM, nullptr,
        mbf2, SZ_DM, DMODEL, nullptr, 0, nullptr, EDIM);
    // 9. LN on dir0 half of mbf2 (in place)
    ln_k<<<dim3(MROWS / 4), blk, 0, stream>>>(mbf2, n1g, n1b);
    // 10. G5: ffh2[dir] = relu(m @ fw1 + fb1)   M=4096 N=1024 K=512
    //     128x64 tile -> (16,32,2) = 1024 blocks = 4/CU
    bgemm3_k<128, 64, 2, false, false><<<dim3(16, 32, 2), blk, 0, stream>>>(
        mbf2, SZ_DM, DMODEL, fw1T, 0, DMODEL, fb1,
        ffh2, U, DFF, nullptr, 0, nullptr, DMODEL);
    // 11. G6 fused (concat-K): out = ffh_f@fw2 + ffh_b@fw2 + 2*fb2 + m_f + m_b
    //     64x64 tile -> (8,64,1) = 512 blocks = 2/CU
    bgemm3_k<64, 64, 5, false, true><<<dim3(8, 64, 1), blk, 0, stream>>>(
        ffh2, U, DFF, fw2T, 0, DFF, fb2,
        nullptr, 0, DMODEL, mbf2, SZ_DM, out, 2 * DFF);
}